// Round 4
// baseline (244.460 us; speedup 1.0000x reference)
//
#include <hip/hip_runtime.h>
#include <hip/hip_bf16.h>

#define B_ 2
#define T_ 2048
#define H_ 1024
#define NH_ 16
#define D_ 64
#define BT_ (B_*T_)
#define SCALE_ 0.125f
#define LOG2E_ 1.4426950408889634f

typedef _Float16 f16x8 __attribute__((ext_vector_type(8)));
typedef float f32x4 __attribute__((ext_vector_type(4)));

#define MFMA(a,b,c) __builtin_amdgcn_mfma_f32_16x16x32_f16((a),(b),(c),0,0,0)
#define EXP2(x) __builtin_amdgcn_exp2f(x)

typedef const __attribute__((address_space(1))) void GV;
typedef __attribute__((address_space(3))) void LV;

// Fragment-tiled layout: matrix [R x C] consumed by MFMA with k-dim = C.
// 16-row tiles, 32-wide k-chunks; chunk block = [quad(k/8)][row%16][k%8] = 512 f16 = 1KB.
__device__ __forceinline__ size_t toff(int r, int c, int C) {
    return (size_t)((r >> 4) * (C >> 5) + (c >> 5)) * 512 + (size_t)(((c & 31) >> 3) * 128 + (r & 15) * 8 + (c & 7));
}
__device__ __forceinline__ f16x8 frag_ld(const _Float16* base, int rt, int kc, int Cc, int l15, int quad) {
    return *(const f16x8*)(base + (size_t)(rt * Cc + kc) * 512 + quad * 128 + l15 * 8);
}

// ---------- prep: cast x, cast Wq/Wk, cast Wv/Wo, zero upper-tri mw — one kernel ----------
__global__ __launch_bounds__(256) void k_prep(const float* __restrict__ x,
                                              const float* __restrict__ Wq, const float* __restrict__ Wk,
                                              const float* __restrict__ Wv, const float* __restrict__ Wo,
                                              _Float16* __restrict__ xb, _Float16* __restrict__ wqk,
                                              _Float16* __restrict__ wvt, _Float16* __restrict__ wot,
                                              float* __restrict__ mw) {
    int blk = blockIdx.x, tid = threadIdx.x;
    if (blk < 2048) {                              // cast x
        int idx = blk * 256 + tid;
        int t = idx >> 7, h0 = (idx & 127) * 8;
        const float* p = x + ((size_t)t << 10) + h0;
        float4 f0 = *(const float4*)p;
        float4 f1 = *(const float4*)(p + 4);
        f16x8 o;
        o[0]=(_Float16)f0.x; o[1]=(_Float16)f0.y; o[2]=(_Float16)f0.z; o[3]=(_Float16)f0.w;
        o[4]=(_Float16)f1.x; o[5]=(_Float16)f1.y; o[6]=(_Float16)f1.z; o[7]=(_Float16)f1.w;
        *(f16x8*)(xb + toff(t, h0, 1024)) = o;
    } else if (blk < 2560) {                       // cast Wq/Wk
        int idx = (blk - 2048) * 256 + tid;
        int head = idx >> 13;
        int rem = idx & 8191;
        int h = rem >> 3;
        int d0 = (rem & 7) * 8;
        const float* pq = Wq + ((size_t)((head << 10) + h)) * 64 + d0;
        const float* pk = Wk + ((size_t)((head << 10) + h)) * 64 + d0;
        float4 q0 = *(const float4*)pq, q1 = *(const float4*)(pq + 4);
        float4 k0 = *(const float4*)pk, k1 = *(const float4*)(pk + 4);
        float qv[8] = {q0.x,q0.y,q0.z,q0.w,q1.x,q1.y,q1.z,q1.w};
        float kv[8] = {k0.x,k0.y,k0.z,k0.w,k1.x,k1.y,k1.z,k1.w};
#pragma unroll
        for (int e = 0; e < 8; e++) {
            int c = head * 64 + d0 + e;
            wqk[toff(c, h, 1024)]        = (_Float16)qv[e];
            wqk[toff(c + 1024, h, 1024)] = (_Float16)kv[e];
        }
    } else if (blk < 2816) {                       // cast Wv/Wo
        int i = (blk - 2560) * 256 + tid;
        int d = i >> 10, h = i & 1023;
        wvt[toff(d, h, 1024)] = (_Float16)Wv[(size_t)h * 64 + d];
        int hh = i >> 6, dd = i & 63;
        wot[toff(hh, dd, 64)] = (_Float16)Wo[(size_t)dd * 1024 + hh];
    } else {                                       // zero upper-tri tiles (992)
        int iz = blk - 2816;
        int b = (iz >= 496) ? 1 : 0;
        int i = iz - b * 496;
        int s64 = (int)((sqrtf(8.f * i + 1.f) + 1.f) * 0.5f);
        if (s64 * (s64 - 1) / 2 > i) s64--;
        if ((s64 + 1) * s64 / 2 <= i) s64++;
        int q64 = i - s64 * (s64 - 1) / 2;         // q64 < s64
        float4 z = {0.f, 0.f, 0.f, 0.f};
#pragma unroll
        for (int it = 0; it < 4; it++) {
            int idx = it * 256 + tid;
            int r = idx >> 4, c4 = idx & 15;
            *(float4*)&mw[(size_t)(b * T_ + q64 * 64 + r) * T_ + s64 * 64 + c4 * 4] = z;
        }
    }
}

// ---------- fused Q||K projection GEMM; vectorized tiled epilogue via LDS transpose ----------
__global__ __launch_bounds__(256) void k_gemm_qk(const _Float16* __restrict__ xb, const _Float16* __restrict__ wqk,
                                                 const float* __restrict__ bq, const float* __restrict__ bk,
                                                 _Float16* __restrict__ qh, _Float16* __restrict__ kh) {
    __shared__ __align__(16) _Float16 As[4096];
    __shared__ __align__(16) _Float16 Bs[4096];
    int bm = blockIdx.x >> 4, bn = blockIdx.x & 15;
    int tid = threadIdx.x, w = tid >> 6, lane = tid & 63, l15 = lane & 15, quad = lane >> 4;
    int rowbase = (w >> 1) * 64, colbase = (w & 1) * 64;
    f32x4 acc[4][4];
#pragma unroll
    for (int i = 0; i < 4; i++)
#pragma unroll
        for (int j = 0; j < 4; j++) acc[i][j] = (f32x4){0.f, 0.f, 0.f, 0.f};

    for (int kk = 0; kk < 32; kk++) {
        __syncthreads();
#pragma unroll
        for (int p = 0; p < 2; p++) {
            int c = w + p * 4;
            __builtin_amdgcn_global_load_lds((GV*)(xb  + ((size_t)((bm * 8 + c) * 32 + kk)) * 512 + lane * 8),
                                             (LV*)(As + c * 512 + lane * 8), 16, 0, 0);
            __builtin_amdgcn_global_load_lds((GV*)(wqk + ((size_t)((bn * 8 + c) * 32 + kk)) * 512 + lane * 8),
                                             (LV*)(Bs + c * 512 + lane * 8), 16, 0, 0);
        }
        __syncthreads();
        f16x8 a[4], bf[4];
#pragma unroll
        for (int i = 0; i < 4; i++) a[i]  = *(const f16x8*)&As[((rowbase >> 4) + i) * 512 + quad * 128 + l15 * 8];
#pragma unroll
        for (int j = 0; j < 4; j++) bf[j] = *(const f16x8*)&Bs[((colbase >> 4) + j) * 512 + quad * 128 + l15 * 8];
#pragma unroll
        for (int i = 0; i < 4; i++)
#pragma unroll
            for (int j = 0; j < 4; j++) acc[i][j] = MFMA(a[i], bf[j], acc[i][j]);
    }
    __syncthreads();                               // all LDS reads done; reuse As/Bs for epilogue staging
    int b = (bm * 128) >> 11;
    int t_base = (bm * 128) & 2047;
    int rtbase = (t_base + rowbase) >> 4;
    bool isq = (bn < 8);
    int c2base = isq ? (bn * 128 + colbase) : (bn * 128 + colbase - 1024);
    int n = c2base >> 6;
    _Float16* dst = (isq ? qh : kh) + (size_t)(n * 2 + b) * 131072;
    const float* bias_p = isq ? bq : bk;
    float qs = SCALE_ * LOG2E_;                    // fold softmax scale + log2e into q
    int i2 = lane >> 4, rowrb = lane & 15;
#pragma unroll
    for (int j = 0; j < 4; j++) {
        float bias = bias_p[c2base + j * 16 + l15];
        _Float16* stg = ((j & 1) ? Bs : As) + w * 1024;
#pragma unroll
        for (int i = 0; i < 4; i++)
#pragma unroll
            for (int r = 0; r < 4; r++) {
                float v = acc[i][j][r] + bias;
                if (isq) v *= qs;
                stg[(i * 16 + quad * 4 + r) * 16 + l15] = (_Float16)v;
            }
#pragma unroll
        for (int oct = 0; oct < 2; oct++) {
            f16x8 val = *(const f16x8*)&stg[(i2 * 16 + rowrb) * 16 + oct * 8];
            int dd0 = j * 16 + oct * 8;
            *(f16x8*)(dst + (size_t)((rtbase + i2) * 2 + (dd0 >> 5)) * 512 + ((dd0 & 31) >> 3) * 128 + rowrb * 8) = val;
        }
    }
}

// ---------- V projection ----------
__global__ __launch_bounds__(256) void k_vproj(const _Float16* __restrict__ xb, const _Float16* __restrict__ wvt,
                                               const float* __restrict__ bv, _Float16* __restrict__ vt) {
    __shared__ float red[4][16][64];
    int tid = threadIdx.x, w = tid >> 6, lane = tid & 63, l15 = lane & 15, quad = lane >> 4;
    int rt = blockIdx.x;
    f32x4 acc[4];
#pragma unroll
    for (int j = 0; j < 4; j++) acc[j] = (f32x4){0.f, 0.f, 0.f, 0.f};
    for (int q = 0; q < 8; q++) {
        int kc = w * 8 + q;
        f16x8 a = frag_ld(xb, rt, kc, 32, l15, quad);
#pragma unroll
        for (int j = 0; j < 4; j++) {
            f16x8 bb = frag_ld(wvt, j, kc, 32, l15, quad);
            acc[j] = MFMA(a, bb, acc[j]);
        }
    }
#pragma unroll
    for (int j = 0; j < 4; j++)
#pragma unroll
        for (int r = 0; r < 4; r++) red[w][quad * 4 + r][j * 16 + l15] = acc[j][r];
    __syncthreads();
    int r = tid >> 4, dg = tid & 15;
    int b = rt >> 7, tt = (rt & 127) * 16 + r;
    _Float16* vtb = vt + (size_t)b * 131072;
#pragma unroll
    for (int e = 0; e < 4; e++) {
        int d = dg * 4 + e;
        float s = red[0][r][d] + red[1][r][d] + red[2][r][d] + red[3][r][d] + bv[d];
        vtb[toff(d, tt, 2048)] = (_Float16)s;
    }
}

// ---------- pass 1: causal row sum-exp2, 4-way K-split partials, pipelined ----------
__global__ __launch_bounds__(256) void k_pass1(const _Float16* __restrict__ qh, const _Float16* __restrict__ kh,
                                               float* __restrict__ lstat4) {
    int tid = threadIdx.x, w = tid >> 6, lane = tid & 63, l15 = lane & 15, quad = lane >> 4;
    int blk = blockIdx.x;                          // 1024 blocks
    int n = blk >> 6, b = (blk >> 5) & 1, strip = blk & 31;
    const _Float16* qb = qh + (size_t)(n * 2 + b) * 131072;
    const _Float16* kp = kh + (size_t)(n * 2 + b) * 131072;
    int rt0 = strip * 4;
    f16x8 aq[4][2];
#pragma unroll
    for (int i = 0; i < 4; i++)
#pragma unroll
        for (int kk = 0; kk < 2; kk++) aq[i][kk] = frag_ld(qb, rt0 + i, kk, 2, l15, quad);
    float l[4][4];
#pragma unroll
    for (int i = 0; i < 4; i++)
#pragma unroll
        for (int r = 0; r < 4; r++) l[i][r] = 0.f;
    int st_lo = w * (strip + 1);
    int st_hi = st_lo + strip + 1;
    f16x8 c0 = frag_ld(kp, st_lo, 0, 2, l15, quad);
    f16x8 c1 = frag_ld(kp, st_lo, 1, 2, l15, quad);
    for (int st = st_lo; st < st_hi; st++) {
        int sn = (st + 1 < st_hi) ? st + 1 : st;
        f16x8 n0 = frag_ld(kp, sn, 0, 2, l15, quad);   // prefetch next while computing current
        f16x8 n1 = frag_ld(kp, sn, 1, 2, l15, quad);
#pragma unroll
        for (int i = 0; i < 4; i++) {
            if (st > rt0 + i) continue;            // wave-uniform (scalar) branch
            f32x4 sc = (f32x4){0.f, 0.f, 0.f, 0.f};
            sc = MFMA(aq[i][0], c0, sc);
            sc = MFMA(aq[i][1], c1, sc);
            if (st == rt0 + i) {
#pragma unroll
                for (int r = 0; r < 4; r++)
                    if (l15 <= quad * 4 + r) l[i][r] += EXP2(sc[r]);
            } else {
#pragma unroll
                for (int r = 0; r < 4; r++) l[i][r] += EXP2(sc[r]);
            }
        }
        c0 = n0; c1 = n1;
    }
#pragma unroll
    for (int off = 1; off < 16; off <<= 1)
#pragma unroll
        for (int i = 0; i < 4; i++)
#pragma unroll
            for (int r = 0; r < 4; r++) l[i][r] += __shfl_xor(l[i][r], off, 64);
    if (l15 == 0) {
        int base = (n * 2 + b) * 2048 + strip * 64;
#pragma unroll
        for (int i = 0; i < 4; i++)
#pragma unroll
            for (int r = 0; r < 4; r++)
                lstat4[(size_t)(base + i * 16 + quad * 4 + r) * 4 + w] = l[i][r];
    }
}

// ---------- pass 2 off-diagonal: no causal mask, head-loop pipelined ----------
__global__ __launch_bounds__(256) void k_pass2o(const _Float16* __restrict__ qh, const _Float16* __restrict__ kh,
                                                const float* __restrict__ lstat4,
                                                float* __restrict__ mw, _Float16* __restrict__ mwh) {
    int iz = blockIdx.x;                           // 992 = 2 x 496 strictly-lower tiles
    int b = (iz >= 496) ? 1 : 0;
    int i = iz - b * 496;
    int q64 = (int)((sqrtf(8.f * i + 1.f) + 1.f) * 0.5f);
    if (q64 * (q64 - 1) / 2 > i) q64--;
    if ((q64 + 1) * q64 / 2 <= i) q64++;
    int s64 = i - q64 * (q64 - 1) / 2;             // s64 < q64
    int tid = threadIdx.x;
    __shared__ float sl[16][64];
    __shared__ __align__(16) _Float16 stg[4][1024];
    for (int ii = tid; ii < 1024; ii += 256) {
        int h = ii >> 6, r = ii & 63;
        const float4 p = *(const float4*)&lstat4[(size_t)((h * 2 + b) * 2048 + q64 * 64 + r) * 4];
        sl[h][r] = 0.0625f / (p.x + p.y + p.z + p.w);   // fold 1/NH
    }
    __syncthreads();
    int w = tid >> 6, lane = tid & 63, l15 = lane & 15, quad = lane >> 4;
    int rw = (w >> 1) * 32, cw = (w & 1) * 32;
    int rt0 = (q64 * 64 + rw) >> 4, st0 = (s64 * 64 + cw) >> 4;
    f16x8 A[2][2][2], K[2][2][2];
#pragma unroll
    for (int ii = 0; ii < 2; ii++)
#pragma unroll
        for (int kk = 0; kk < 2; kk++) {
            A[0][ii][kk] = frag_ld(qh + (size_t)b * 131072, rt0 + ii, kk, 2, l15, quad);
            K[0][ii][kk] = frag_ld(kh + (size_t)b * 131072, st0 + ii, kk, 2, l15, quad);
        }
    f32x4 macc[2][2];
#pragma unroll
    for (int ii = 0; ii < 2; ii++)
#pragma unroll
        for (int j = 0; j < 2; j++) macc[ii][j] = (f32x4){0.f, 0.f, 0.f, 0.f};
#pragma unroll
    for (int n = 0; n < NH_; n++) {
        int cur = n & 1;
        if (n < NH_ - 1) {
            const _Float16* qb = qh + (size_t)((n + 1) * 2 + b) * 131072;
            const _Float16* kp = kh + (size_t)((n + 1) * 2 + b) * 131072;
#pragma unroll
            for (int ii = 0; ii < 2; ii++)
#pragma unroll
                for (int kk = 0; kk < 2; kk++) {
                    A[cur ^ 1][ii][kk] = frag_ld(qb, rt0 + ii, kk, 2, l15, quad);
                    K[cur ^ 1][ii][kk] = frag_ld(kp, st0 + ii, kk, 2, l15, quad);
                }
        }
        f32x4 slv[2];
#pragma unroll
        for (int ii = 0; ii < 2; ii++) slv[ii] = *(const f32x4*)&sl[n][rw + ii * 16 + quad * 4];
#pragma unroll
        for (int ii = 0; ii < 2; ii++)
#pragma unroll
            for (int j = 0; j < 2; j++) {
                f32x4 sc = (f32x4){0.f, 0.f, 0.f, 0.f};
                sc = MFMA(A[cur][ii][0], K[cur][j][0], sc);
                sc = MFMA(A[cur][ii][1], K[cur][j][1], sc);
#pragma unroll
                for (int r = 0; r < 4; r++) macc[ii][j][r] += EXP2(sc[r]) * slv[ii][r];
            }
    }
    // fp32 mw store (semi-coalesced 64B runs)
    float* mwb = mw + (size_t)b * T_ * T_;
#pragma unroll
    for (int ii = 0; ii < 2; ii++)
#pragma unroll
        for (int j = 0; j < 2; j++)
#pragma unroll
            for (int r = 0; r < 4; r++) {
                int tg = q64 * 64 + rw + ii * 16 + quad * 4 + r;
                int sg = s64 * 64 + cw + j * 16 + l15;
                mwb[(size_t)tg * T_ + sg] = macc[ii][j][r];
            }
    // f16 tiled store via in-wave LDS transpose -> 2x f16x8 per lane
    _Float16* ws16 = stg[w];
#pragma unroll
    for (int ii = 0; ii < 2; ii++)
#pragma unroll
        for (int j = 0; j < 2; j++)
#pragma unroll
            for (int r = 0; r < 4; r++) {
                int cl = cw + j * 16 + l15;        // col local to 64-tile? cw+j*16+l15 in [cw, cw+32)
                int clw = j * 16 + l15;            // col local to wave's 32-strip
                (void)cl;
                ws16[ii * 512 + (clw >> 3) * 128 + (quad * 4 + r) * 8 + (clw & 7)] = (_Float16)macc[ii][j][r];
            }
    _Float16* mhb = mwh + (size_t)b * 4194304;
    int rowrb = lane & 15, qc = lane >> 4;         // qc in 0..3
#pragma unroll
    for (int ii = 0; ii < 2; ii++) {
        f16x8 val = *(const f16x8*)&ws16[ii * 512 + qc * 128 + rowrb * 8];
        *(f16x8*)(mhb + (size_t)((rt0 + ii) * 64 + ((s64 * 64 + cw) >> 5)) * 512 + qc * 128 + rowrb * 8) = val;
    }
}

// ---------- pass 2 diagonal: 64 blocks, masked ----------
__global__ __launch_bounds__(256) void k_pass2d(const _Float16* __restrict__ qh, const _Float16* __restrict__ kh,
                                                const float* __restrict__ lstat4,
                                                float* __restrict__ mw, _Float16* __restrict__ mwh) {
    int blk = blockIdx.x;
    int b = blk >> 5, q64 = blk & 31, s64 = q64;
    int tid = threadIdx.x;
    __shared__ float sl[16][64];
    for (int ii = tid; ii < 1024; ii += 256) {
        int h = ii >> 6, r = ii & 63;
        const float4 p = *(const float4*)&lstat4[(size_t)((h * 2 + b) * 2048 + q64 * 64 + r) * 4];
        sl[h][r] = 0.0625f / (p.x + p.y + p.z + p.w);
    }
    __syncthreads();
    int w = tid >> 6, lane = tid & 63, l15 = lane & 15, quad = lane >> 4;
    int rw = (w >> 1) * 32, cw = (w & 1) * 32;
    int rt0 = (q64 * 64 + rw) >> 4, st0 = (s64 * 64 + cw) >> 4;
    f32x4 macc[2][2];
#pragma unroll
    for (int ii = 0; ii < 2; ii++)
#pragma unroll
        for (int j = 0; j < 2; j++) macc[ii][j] = (f32x4){0.f, 0.f, 0.f, 0.f};
#pragma unroll
    for (int n = 0; n < NH_; n++) {
        const _Float16* qb = qh + (size_t)(n * 2 + b) * 131072;
        const _Float16* kp = kh + (size_t)(n * 2 + b) * 131072;
        f16x8 aq[2][2], kb[2][2];
#pragma unroll
        for (int ii = 0; ii < 2; ii++)
#pragma unroll
            for (int kk = 0; kk < 2; kk++) {
                aq[ii][kk] = frag_ld(qb, rt0 + ii, kk, 2, l15, quad);
                kb[ii][kk] = frag_ld(kp, st0 + ii, kk, 2, l15, quad);
            }
        f32x4 slv[2];
#pragma unroll
        for (int ii = 0; ii < 2; ii++) slv[ii] = *(const f32x4*)&sl[n][rw + ii * 16 + quad * 4];
#pragma unroll
        for (int ii = 0; ii < 2; ii++)
#pragma unroll
            for (int j = 0; j < 2; j++) {
                f32x4 sc = (f32x4){0.f, 0.f, 0.f, 0.f};
                sc = MFMA(aq[ii][0], kb[j][0], sc);
                sc = MFMA(aq[ii][1], kb[j][1], sc);
                int sg = s64 * 64 + cw + j * 16 + l15;
#pragma unroll
                for (int r = 0; r < 4; r++) {
                    int tg = q64 * 64 + rw + ii * 16 + quad * 4 + r;
                    macc[ii][j][r] += (sg <= tg) ? EXP2(sc[r]) * slv[ii][r] : 0.f;
                }
            }
    }
    float* mwb = mw + (size_t)b * T_ * T_;
    _Float16* mhb = mwh + (size_t)b * 4194304;
#pragma unroll
    for (int ii = 0; ii < 2; ii++)
#pragma unroll
        for (int j = 0; j < 2; j++)
#pragma unroll
            for (int r = 0; r < 4; r++) {
                int tg = q64 * 64 + rw + ii * 16 + quad * 4 + r;
                int sg = s64 * 64 + cw + j * 16 + l15;
                float v = macc[ii][j][r];
                mwb[(size_t)tg * T_ + sg] = v;
                mhb[toff(tg, sg, 2048)] = (_Float16)v;
            }
}

// ---------- pass 3a: mean_head partials, kc-loop pipelined ----------
__global__ __launch_bounds__(256) void k_pass3a(const _Float16* __restrict__ mwh, const _Float16* __restrict__ vt,
                                                _Float16* __restrict__ mhp) {
    __shared__ float red[4][16][64];
    int tid = threadIdx.x, w = tid >> 6, lane = tid & 63, l15 = lane & 15, quad = lane >> 4;
    int blk = blockIdx.x;                          // 1024 = 256 tiles x 4 quarters
    int tile = blk >> 2, q = blk & 3;
    int b = tile >> 7, rtb = tile & 127;
    const _Float16* mb = mwh + (size_t)b * 4194304;
    const _Float16* vb = vt + (size_t)b * 131072;
    int nkc = (rtb * 16 + 47) >> 5;
    int qlo = q * 16;
    int qhi = min(qlo + 16, nkc);
    f32x4 acc[4];
#pragma unroll
    for (int j = 0; j < 4; j++) acc[j] = (f32x4){0.f, 0.f, 0.f, 0.f};
    int kc = qlo + w;
    if (kc < qhi) {
        f16x8 Ac = frag_ld(mb, rtb, kc, 64, l15, quad);
        f16x8 Bc[4];
#pragma unroll
        for (int j = 0; j < 4; j++) Bc[j] = frag_ld(vb, j, kc, 64, l15, quad);
        for (; kc < qhi; kc += 4) {
            int kn = (kc + 4 < qhi) ? kc + 4 : kc;
            f16x8 An = frag_ld(mb, rtb, kn, 64, l15, quad);
            f16x8 Bn[4];
#pragma unroll
            for (int j = 0; j < 4; j++) Bn[j] = frag_ld(vb, j, kn, 64, l15, quad);
#pragma unroll
            for (int j = 0; j < 4; j++) acc[j] = MFMA(Ac, Bc[j], acc[j]);
            Ac = An;
#pragma unroll
            for (int j = 0; j < 4; j++) Bc[j] = Bn[j];
        }
    }
#pragma unroll
    for (int j = 0; j < 4; j++)
#pragma unroll
        for (int r = 0; r < 4; r++) red[w][quad * 4 + r][j * 16 + l15] = acc[j][r];
    __syncthreads();
    int r = tid >> 4, dg = tid & 15;
    _Float16* dst = mhp + (size_t)q * 262144;
#pragma unroll
    for (int e = 0; e < 4; e++) {
        int d = dg * 4 + e;
        float s = red[0][r][d] + red[1][r][d] + red[2][r][d] + red[3][r][d];
        dst[toff(tile * 16 + r, d, 64)] = (_Float16)s;
    }
}

// ---------- pass 3b: out = (sum of 4 partials) @ Wo + bo ----------
__global__ __launch_bounds__(256) void k_pass3b(const _Float16* __restrict__ mhp, const _Float16* __restrict__ wot,
                                                const float* __restrict__ bo, float* __restrict__ out0) {
    int bm = blockIdx.x >> 4, bn = blockIdx.x & 15;
    int tid = threadIdx.x, w = tid >> 6, lane = tid & 63, l15 = lane & 15, quad = lane >> 4;
    int rt = bm * 4 + w;
    f16x8 a0[4], a1[4];
#pragma unroll
    for (int q = 0; q < 4; q++) {
        const _Float16* mb = mhp + (size_t)q * 262144;
        a0[q] = frag_ld(mb, rt, 0, 2, l15, quad);
        a1[q] = frag_ld(mb, rt, 1, 2, l15, quad);
    }
    f32x4 acc[4];
#pragma unroll
    for (int j = 0; j < 4; j++) acc[j] = (f32x4){0.f, 0.f, 0.f, 0.f};
#pragma unroll
    for (int j = 0; j < 4; j++) {
        f16x8 b0 = frag_ld(wot, bn * 4 + j, 0, 2, l15, quad);
        f16x8 b1 = frag_ld(wot, bn * 4 + j, 1, 2, l15, quad);
#pragma unroll
        for (int q = 0; q < 4; q++) {
            acc[j] = MFMA(a0[q], b0, acc[j]);
            acc[j] = MFMA(a1[q], b1, acc[j]);
        }
    }
#pragma unroll
    for (int j = 0; j < 4; j++)
#pragma unroll
        for (int r = 0; r < 4; r++) {
            int row = rt * 16 + quad * 4 + r;
            int col = bn * 64 + j * 16 + l15;
            out0[(size_t)row * 1024 + col] = acc[j][r] + bo[col];
        }
}

extern "C" void kernel_launch(void* const* d_in, const int* in_sizes, int n_in,
                              void* d_out, int out_size, void* d_ws, size_t ws_size,
                              hipStream_t stream) {
    const float* x  = (const float*)d_in[0];
    const float* Wq = (const float*)d_in[1];
    const float* bq = (const float*)d_in[2];
    const float* Wk = (const float*)d_in[3];
    const float* bk = (const float*)d_in[4];
    const float* Wv = (const float*)d_in[5];
    const float* bv = (const float*)d_in[6];
    const float* Wo = (const float*)d_in[7];
    const float* bo = (const float*)d_in[8];
    char* ws = (char*)d_ws;
    _Float16* xb    = (_Float16*)(ws + 0);         // 8 MB (dead after vproj)
    _Float16* wqk   = (_Float16*)(ws + 8388608);   // 4 MB (dead after gemm)
    _Float16* wvt   = (_Float16*)(ws + 12582912);  // 128 KB (dead after vproj)
    _Float16* mwh   = (_Float16*)(ws + 0);         // 16 MB overlay
    _Float16* qh    = (_Float16*)(ws + 16777216);  // 8 MB
    _Float16* kh    = (_Float16*)(ws + 25165824);  // 8 MB
    _Float16* vt    = (_Float16*)(ws + 33554432);  // 512 KB
    float*    lstat4= (float*)   (ws + 34078720);  // 1 MB
    _Float16* mhp   = (_Float16*)(ws + 35127296);  // 2 MB (4 partials)
    _Float16* wot   = (_Float16*)(ws + 37224448);  // 128 KB
    float* out0 = (float*)d_out;
    float* mw   = out0 + (size_t)BT_ * H_;

    k_prep    <<<3808, 256, 0, stream>>>(x, Wq, Wk, Wv, Wo, xb, wqk, wvt, wot, mw);
    k_gemm_qk <<<512,  256, 0, stream>>>(xb, wqk, bq, bk, qh, kh);
    k_vproj   <<<256,  256, 0, stream>>>(xb, wvt, bv, vt);
    k_pass1   <<<1024, 256, 0, stream>>>(qh, kh, lstat4);
    k_pass2o  <<<992,  256, 0, stream>>>(qh, kh, lstat4, mw, mwh);
    k_pass2d  <<<64,   256, 0, stream>>>(qh, kh, lstat4, mw, mwh);
    k_pass3a  <<<1024, 256, 0, stream>>>(mwh, vt, mhp);
    k_pass3b  <<<1024, 256, 0, stream>>>(mhp, wot, bo, out0);
}

// Round 5
// 219.769 us; speedup vs baseline: 1.1123x; 1.1123x over previous
//
#include <hip/hip_runtime.h>
#include <hip/hip_bf16.h>

#define B_ 2
#define T_ 2048
#define H_ 1024
#define NH_ 16
#define D_ 64
#define BT_ (B_*T_)
#define SCALE_ 0.125f
#define LOG2E_ 1.4426950408889634f

typedef _Float16 f16x8 __attribute__((ext_vector_type(8)));
typedef float f32x4 __attribute__((ext_vector_type(4)));

#define MFMA(a,b,c) __builtin_amdgcn_mfma_f32_16x16x32_f16((a),(b),(c),0,0,0)
#define EXP2(x) __builtin_amdgcn_exp2f(x)

typedef const __attribute__((address_space(1))) void GV;
typedef __attribute__((address_space(3))) void LV;

// Fragment-tiled layout: matrix [R x C] consumed by MFMA with k-dim = C.
// 16-row tiles, 32-wide k-chunks; chunk block = [quad(k/8)][row%16][k%8] = 512 f16 = 1KB.
__device__ __forceinline__ size_t toff(int r, int c, int C) {
    return (size_t)((r >> 4) * (C >> 5) + (c >> 5)) * 512 + (size_t)(((c & 31) >> 3) * 128 + (r & 15) * 8 + (c & 7));
}
__device__ __forceinline__ f16x8 frag_ld(const _Float16* base, int rt, int kc, int Cc, int l15, int quad) {
    return *(const f16x8*)(base + (size_t)(rt * Cc + kc) * 512 + quad * 128 + l15 * 8);
}

// ---------- prep: cast x, cast Wq/Wk, cast Wv/Wo, zero upper-tri mw — one kernel ----------
__global__ __launch_bounds__(256) void k_prep(const float* __restrict__ x,
                                              const float* __restrict__ Wq, const float* __restrict__ Wk,
                                              const float* __restrict__ Wv, const float* __restrict__ Wo,
                                              _Float16* __restrict__ xb, _Float16* __restrict__ wqk,
                                              _Float16* __restrict__ wvt, _Float16* __restrict__ wot,
                                              float* __restrict__ mw) {
    int blk = blockIdx.x, tid = threadIdx.x;
    if (blk < 2048) {                              // cast x
        int idx = blk * 256 + tid;
        int t = idx >> 7, h0 = (idx & 127) * 8;
        const float* p = x + ((size_t)t << 10) + h0;
        float4 f0 = *(const float4*)p;
        float4 f1 = *(const float4*)(p + 4);
        f16x8 o;
        o[0]=(_Float16)f0.x; o[1]=(_Float16)f0.y; o[2]=(_Float16)f0.z; o[3]=(_Float16)f0.w;
        o[4]=(_Float16)f1.x; o[5]=(_Float16)f1.y; o[6]=(_Float16)f1.z; o[7]=(_Float16)f1.w;
        *(f16x8*)(xb + toff(t, h0, 1024)) = o;
    } else if (blk < 2560) {                       // cast Wq/Wk
        int idx = (blk - 2048) * 256 + tid;
        int head = idx >> 13;
        int rem = idx & 8191;
        int h = rem >> 3;
        int d0 = (rem & 7) * 8;
        const float* pq = Wq + ((size_t)((head << 10) + h)) * 64 + d0;
        const float* pk = Wk + ((size_t)((head << 10) + h)) * 64 + d0;
        float4 q0 = *(const float4*)pq, q1 = *(const float4*)(pq + 4);
        float4 k0 = *(const float4*)pk, k1 = *(const float4*)(pk + 4);
        float qv[8] = {q0.x,q0.y,q0.z,q0.w,q1.x,q1.y,q1.z,q1.w};
        float kv[8] = {k0.x,k0.y,k0.z,k0.w,k1.x,k1.y,k1.z,k1.w};
#pragma unroll
        for (int e = 0; e < 8; e++) {
            int c = head * 64 + d0 + e;
            wqk[toff(c, h, 1024)]        = (_Float16)qv[e];
            wqk[toff(c + 1024, h, 1024)] = (_Float16)kv[e];
        }
    } else if (blk < 2816) {                       // cast Wv/Wo
        int i = (blk - 2560) * 256 + tid;
        int d = i >> 10, h = i & 1023;
        wvt[toff(d, h, 1024)] = (_Float16)Wv[(size_t)h * 64 + d];
        int hh = i >> 6, dd = i & 63;
        wot[toff(hh, dd, 64)] = (_Float16)Wo[(size_t)dd * 1024 + hh];
    } else {                                       // zero upper-tri tiles (992)
        int iz = blk - 2816;
        int b = (iz >= 496) ? 1 : 0;
        int i = iz - b * 496;
        int s64 = (int)((sqrtf(8.f * i + 1.f) + 1.f) * 0.5f);
        if (s64 * (s64 - 1) / 2 > i) s64--;
        if ((s64 + 1) * s64 / 2 <= i) s64++;
        int q64 = i - s64 * (s64 - 1) / 2;         // q64 < s64
        float4 z = {0.f, 0.f, 0.f, 0.f};
#pragma unroll
        for (int it = 0; it < 4; it++) {
            int idx = it * 256 + tid;
            int r = idx >> 4, c4 = idx & 15;
            *(float4*)&mw[(size_t)(b * T_ + q64 * 64 + r) * T_ + s64 * 64 + c4 * 4] = z;
        }
    }
}

// ---------- fused Q||K projection GEMM; vectorized tiled epilogue via LDS transpose ----------
__global__ __launch_bounds__(256) void k_gemm_qk(const _Float16* __restrict__ xb, const _Float16* __restrict__ wqk,
                                                 const float* __restrict__ bq, const float* __restrict__ bk,
                                                 _Float16* __restrict__ qh, _Float16* __restrict__ kh) {
    __shared__ __align__(16) _Float16 As[4096];
    __shared__ __align__(16) _Float16 Bs[4096];
    int bm = blockIdx.x >> 4, bn = blockIdx.x & 15;
    int tid = threadIdx.x, w = tid >> 6, lane = tid & 63, l15 = lane & 15, quad = lane >> 4;
    int rowbase = (w >> 1) * 64, colbase = (w & 1) * 64;
    f32x4 acc[4][4];
#pragma unroll
    for (int i = 0; i < 4; i++)
#pragma unroll
        for (int j = 0; j < 4; j++) acc[i][j] = (f32x4){0.f, 0.f, 0.f, 0.f};

    for (int kk = 0; kk < 32; kk++) {
        __syncthreads();
#pragma unroll
        for (int p = 0; p < 2; p++) {
            int c = w + p * 4;
            __builtin_amdgcn_global_load_lds((GV*)(xb  + ((size_t)((bm * 8 + c) * 32 + kk)) * 512 + lane * 8),
                                             (LV*)(As + c * 512 + lane * 8), 16, 0, 0);
            __builtin_amdgcn_global_load_lds((GV*)(wqk + ((size_t)((bn * 8 + c) * 32 + kk)) * 512 + lane * 8),
                                             (LV*)(Bs + c * 512 + lane * 8), 16, 0, 0);
        }
        __syncthreads();
        f16x8 a[4], bf[4];
#pragma unroll
        for (int i = 0; i < 4; i++) a[i]  = *(const f16x8*)&As[((rowbase >> 4) + i) * 512 + quad * 128 + l15 * 8];
#pragma unroll
        for (int j = 0; j < 4; j++) bf[j] = *(const f16x8*)&Bs[((colbase >> 4) + j) * 512 + quad * 128 + l15 * 8];
#pragma unroll
        for (int i = 0; i < 4; i++)
#pragma unroll
            for (int j = 0; j < 4; j++) acc[i][j] = MFMA(a[i], bf[j], acc[i][j]);
    }
    __syncthreads();                               // reuse As/Bs for epilogue staging
    int b = (bm * 128) >> 11;
    int t_base = (bm * 128) & 2047;
    int rtbase = (t_base + rowbase) >> 4;
    bool isq = (bn < 8);
    int c2base = isq ? (bn * 128 + colbase) : (bn * 128 + colbase - 1024);
    int n = c2base >> 6;
    _Float16* dst = (isq ? qh : kh) + (size_t)(n * 2 + b) * 131072;
    const float* bias_p = isq ? bq : bk;
    float qs = SCALE_ * LOG2E_;                    // fold softmax scale + log2e into q
    int i2 = lane >> 4, rowrb = lane & 15;
#pragma unroll
    for (int j = 0; j < 4; j++) {
        float bias = bias_p[c2base + j * 16 + l15];
        _Float16* stg = ((j & 1) ? Bs : As) + w * 1024;
#pragma unroll
        for (int i = 0; i < 4; i++)
#pragma unroll
            for (int r = 0; r < 4; r++) {
                float v = acc[i][j][r] + bias;
                if (isq) v *= qs;
                stg[(i * 16 + quad * 4 + r) * 16 + l15] = (_Float16)v;
            }
#pragma unroll
        for (int oct = 0; oct < 2; oct++) {
            f16x8 val = *(const f16x8*)&stg[(i2 * 16 + rowrb) * 16 + oct * 8];
            int dd0 = j * 16 + oct * 8;
            *(f16x8*)(dst + (size_t)((rtbase + i2) * 2 + (dd0 >> 5)) * 512 + ((dd0 & 31) >> 3) * 128 + rowrb * 8) = val;
        }
    }
}

// ---------- V projection ----------
__global__ __launch_bounds__(256) void k_vproj(const _Float16* __restrict__ xb, const _Float16* __restrict__ wvt,
                                               const float* __restrict__ bv, _Float16* __restrict__ vt) {
    __shared__ float red[4][16][64];
    int tid = threadIdx.x, w = tid >> 6, lane = tid & 63, l15 = lane & 15, quad = lane >> 4;
    int rt = blockIdx.x;
    f32x4 acc[4];
#pragma unroll
    for (int j = 0; j < 4; j++) acc[j] = (f32x4){0.f, 0.f, 0.f, 0.f};
    for (int q = 0; q < 8; q++) {
        int kc = w * 8 + q;
        f16x8 a = frag_ld(xb, rt, kc, 32, l15, quad);
#pragma unroll
        for (int j = 0; j < 4; j++) {
            f16x8 bb = frag_ld(wvt, j, kc, 32, l15, quad);
            acc[j] = MFMA(a, bb, acc[j]);
        }
    }
#pragma unroll
    for (int j = 0; j < 4; j++)
#pragma unroll
        for (int r = 0; r < 4; r++) red[w][quad * 4 + r][j * 16 + l15] = acc[j][r];
    __syncthreads();
    int r = tid >> 4, dg = tid & 15;
    int b = rt >> 7, tt = (rt & 127) * 16 + r;
    _Float16* vtb = vt + (size_t)b * 131072;
#pragma unroll
    for (int e = 0; e < 4; e++) {
        int d = dg * 4 + e;
        float s = red[0][r][d] + red[1][r][d] + red[2][r][d] + red[3][r][d] + bv[d];
        vtb[toff(d, tt, 2048)] = (_Float16)s;
    }
}

// ---------- pass 1: causal row sum-exp2, 4-way K-split partials ----------
__global__ __launch_bounds__(256) void k_pass1(const _Float16* __restrict__ qh, const _Float16* __restrict__ kh,
                                               float* __restrict__ lstat4) {
    int tid = threadIdx.x, w = tid >> 6, lane = tid & 63, l15 = lane & 15, quad = lane >> 4;
    int blk = blockIdx.x;                          // 1024 blocks
    int n = blk >> 6, b = (blk >> 5) & 1, strip = blk & 31;
    const _Float16* qb = qh + (size_t)(n * 2 + b) * 131072;
    const _Float16* kp = kh + (size_t)(n * 2 + b) * 131072;
    int rt0 = strip * 4;
    f16x8 aq[4][2];
#pragma unroll
    for (int i = 0; i < 4; i++)
#pragma unroll
        for (int kk = 0; kk < 2; kk++) aq[i][kk] = frag_ld(qb, rt0 + i, kk, 2, l15, quad);
    float l[4][4];
#pragma unroll
    for (int i = 0; i < 4; i++)
#pragma unroll
        for (int r = 0; r < 4; r++) l[i][r] = 0.f;
    int st_lo = w * (strip + 1);
    int st_hi = st_lo + strip + 1;
    for (int st = st_lo; st < st_hi; st++) {
        f16x8 c0 = frag_ld(kp, st, 0, 2, l15, quad);
        f16x8 c1 = frag_ld(kp, st, 1, 2, l15, quad);
#pragma unroll
        for (int i = 0; i < 4; i++) {
            if (st > rt0 + i) continue;            // wave-uniform branch
            f32x4 sc = (f32x4){0.f, 0.f, 0.f, 0.f};
            sc = MFMA(aq[i][0], c0, sc);
            sc = MFMA(aq[i][1], c1, sc);
            if (st == rt0 + i) {
#pragma unroll
                for (int r = 0; r < 4; r++)
                    if (l15 <= quad * 4 + r) l[i][r] += EXP2(sc[r]);
            } else {
#pragma unroll
                for (int r = 0; r < 4; r++) l[i][r] += EXP2(sc[r]);
            }
        }
    }
#pragma unroll
    for (int off = 1; off < 16; off <<= 1)
#pragma unroll
        for (int i = 0; i < 4; i++)
#pragma unroll
            for (int r = 0; r < 4; r++) l[i][r] += __shfl_xor(l[i][r], off, 64);
    if (l15 == 0) {
        int base = (n * 2 + b) * 2048 + strip * 64;
#pragma unroll
        for (int i = 0; i < 4; i++)
#pragma unroll
            for (int r = 0; r < 4; r++)
                lstat4[(size_t)(base + i * 16 + quad * 4 + r) * 4 + w] = l[i][r];
    }
}

// ---------- pass 2 off-diagonal: 128q x 64s tiles, LDS-staged K, XCD-banded ----------
__global__ __launch_bounds__(256) void k_pass2o(const _Float16* __restrict__ qh, const _Float16* __restrict__ kh,
                                                const float* __restrict__ lstat4,
                                                float* __restrict__ mw, _Float16* __restrict__ mwh) {
    __shared__ float sl[16][128];
    __shared__ __align__(16) _Float16 kst[4096];   // 8 KB K-tile stage (reused for store transpose)
    int blk = blockIdx.x;                          // 480 = 2b x 240
    int b = (blk >= 240) ? 1 : 0;
    int i0 = blk - 240 * b;
    int i = (i0 & 7) * 30 + (i0 >> 3);             // XCD-banded: blk%8 -> contiguous 30-tile band
    int p = (int)((1.f + sqrtf(4.f * i + 1.f)) * 0.5f);
    while (p * (p - 1) > i) p--;
    while (p * (p + 1) <= i) p++;
    int s64 = i - p * (p - 1);                     // s64 in [0, 2p): strictly below 128-row strip p
    int tid = threadIdx.x, w = tid >> 6, lane = tid & 63, l15 = lane & 15, quad = lane >> 4;
    for (int ii = tid; ii < 2048; ii += 256) {
        int h = ii >> 7, r = ii & 127;
        const float4 pl = *(const float4*)&lstat4[(size_t)((h * 2 + b) * 2048 + p * 128 + r) * 4];
        sl[h][r] = 0.0625f / (pl.x + pl.y + pl.z + pl.w);
    }
    int rw = w * 32;
    int rt0 = (p * 128 + rw) >> 4;                 // q row-tile base (2 per wave)
    int st0 = s64 * 4;                             // k row-tile base (4 per block)
    f32x4 macc[2][4];
#pragma unroll
    for (int ii = 0; ii < 2; ii++)
#pragma unroll
        for (int j = 0; j < 4; j++) macc[ii][j] = (f32x4){0.f, 0.f, 0.f, 0.f};

    for (int n = 0; n < NH_; n++) {
        const _Float16* qb = qh + (size_t)(n * 2 + b) * 131072;
        const _Float16* kp = kh + (size_t)(n * 2 + b) * 131072;
        __syncthreads();                           // prior iter's kst reads drained
#pragma unroll
        for (int inst = 0; inst < 2; inst++) {
            int c = inst * 4 + w;                  // chunk 0..7
            int gc = (st0 + (c >> 1)) * 2 + (c & 1);
            __builtin_amdgcn_global_load_lds((GV*)(kp + (size_t)gc * 512 + lane * 8),
                                             (LV*)(kst + c * 512 + lane * 8), 16, 0, 0);
        }
        f16x8 A[2][2];
#pragma unroll
        for (int ii = 0; ii < 2; ii++)
#pragma unroll
            for (int kc = 0; kc < 2; kc++) A[ii][kc] = frag_ld(qb, rt0 + ii, kc, 2, l15, quad);
        __syncthreads();                           // kst staged (A also drained)
        f32x4 slv[2];
#pragma unroll
        for (int ii = 0; ii < 2; ii++) slv[ii] = *(const f32x4*)&sl[n][rw + ii * 16 + quad * 4];
#pragma unroll
        for (int j = 0; j < 4; j++) {
            f16x8 K0 = *(const f16x8*)&kst[(j * 2 + 0) * 512 + quad * 128 + l15 * 8];
            f16x8 K1 = *(const f16x8*)&kst[(j * 2 + 1) * 512 + quad * 128 + l15 * 8];
#pragma unroll
            for (int ii = 0; ii < 2; ii++) {
                f32x4 sc = (f32x4){0.f, 0.f, 0.f, 0.f};
                sc = MFMA(A[ii][0], K0, sc);
                sc = MFMA(A[ii][1], K1, sc);
#pragma unroll
                for (int r = 0; r < 4; r++) macc[ii][j][r] += EXP2(sc[r]) * slv[ii][r];
            }
        }
    }
    __syncthreads();                               // done with kst as K stage
    // fp32 mw store
    float* mwb = mw + (size_t)b * T_ * T_;
#pragma unroll
    for (int ii = 0; ii < 2; ii++)
#pragma unroll
        for (int j = 0; j < 4; j++)
#pragma unroll
            for (int r = 0; r < 4; r++) {
                int tg = p * 128 + rw + ii * 16 + quad * 4 + r;
                int sg = s64 * 64 + j * 16 + l15;
                mwb[(size_t)tg * T_ + sg] = macc[ii][j][r];
            }
    // f16 tiled store via per-wave LDS transpose (2 rounds of 32 cols)
    _Float16* mhb = mwh + (size_t)b * 4194304;
    _Float16* ws16 = kst + w * 1024;
    int rowrb = lane & 15, qc = lane >> 4;
#pragma unroll
    for (int cc = 0; cc < 2; cc++) {
#pragma unroll
        for (int ii = 0; ii < 2; ii++)
#pragma unroll
            for (int j2 = 0; j2 < 2; j2++)
#pragma unroll
                for (int r = 0; r < 4; r++) {
                    int clw = j2 * 16 + l15;
                    ws16[ii * 512 + (clw >> 3) * 128 + (quad * 4 + r) * 8 + (clw & 7)] =
                        (_Float16)macc[ii][cc * 2 + j2][r];
                }
#pragma unroll
        for (int ii = 0; ii < 2; ii++) {
            f16x8 val = *(const f16x8*)&ws16[ii * 512 + qc * 128 + rowrb * 8];
            *(f16x8*)(mhb + (size_t)((rt0 + ii) * 64 + (s64 * 2 + cc)) * 512 + qc * 128 + rowrb * 8) = val;
        }
    }
}

// ---------- pass 2 diagonal + leftover tiles: 96 blocks, masked 64x64 ----------
__global__ __launch_bounds__(256) void k_pass2d(const _Float16* __restrict__ qh, const _Float16* __restrict__ kh,
                                                const float* __restrict__ lstat4,
                                                float* __restrict__ mw, _Float16* __restrict__ mwh) {
    int blk = blockIdx.x;                          // 96 = 2b x (32 diag + 16 leftover)
    int b = (blk >= 48) ? 1 : 0;
    int j0 = blk - 48 * b;
    int q64 = (j0 < 32) ? j0 : (2 * (j0 - 32) + 1);
    int s64 = (j0 < 32) ? j0 : (2 * (j0 - 32));
    int tid = threadIdx.x;
    __shared__ float sl[16][64];
    for (int ii = tid; ii < 1024; ii += 256) {
        int h = ii >> 6, r = ii & 63;
        const float4 p = *(const float4*)&lstat4[(size_t)((h * 2 + b) * 2048 + q64 * 64 + r) * 4];
        sl[h][r] = 0.0625f / (p.x + p.y + p.z + p.w);
    }
    __syncthreads();
    int w = tid >> 6, lane = tid & 63, l15 = lane & 15, quad = lane >> 4;
    int rw = (w >> 1) * 32, cw = (w & 1) * 32;
    int rt0 = (q64 * 64 + rw) >> 4, st0 = (s64 * 64 + cw) >> 4;
    f32x4 macc[2][2];
#pragma unroll
    for (int ii = 0; ii < 2; ii++)
#pragma unroll
        for (int j = 0; j < 2; j++) macc[ii][j] = (f32x4){0.f, 0.f, 0.f, 0.f};
#pragma unroll
    for (int n = 0; n < NH_; n++) {
        const _Float16* qb = qh + (size_t)(n * 2 + b) * 131072;
        const _Float16* kp = kh + (size_t)(n * 2 + b) * 131072;
        f16x8 aq[2][2], kb[2][2];
#pragma unroll
        for (int ii = 0; ii < 2; ii++)
#pragma unroll
            for (int kk = 0; kk < 2; kk++) {
                aq[ii][kk] = frag_ld(qb, rt0 + ii, kk, 2, l15, quad);
                kb[ii][kk] = frag_ld(kp, st0 + ii, kk, 2, l15, quad);
            }
        f32x4 slv[2];
#pragma unroll
        for (int ii = 0; ii < 2; ii++) slv[ii] = *(const f32x4*)&sl[n][rw + ii * 16 + quad * 4];
#pragma unroll
        for (int ii = 0; ii < 2; ii++)
#pragma unroll
            for (int j = 0; j < 2; j++) {
                f32x4 sc = (f32x4){0.f, 0.f, 0.f, 0.f};
                sc = MFMA(aq[ii][0], kb[j][0], sc);
                sc = MFMA(aq[ii][1], kb[j][1], sc);
                int sg = s64 * 64 + cw + j * 16 + l15;
#pragma unroll
                for (int r = 0; r < 4; r++) {
                    int tg = q64 * 64 + rw + ii * 16 + quad * 4 + r;
                    macc[ii][j][r] += (sg <= tg) ? EXP2(sc[r]) * slv[ii][r] : 0.f;
                }
            }
    }
    float* mwb = mw + (size_t)b * T_ * T_;
    _Float16* mhb = mwh + (size_t)b * 4194304;
#pragma unroll
    for (int ii = 0; ii < 2; ii++)
#pragma unroll
        for (int j = 0; j < 2; j++)
#pragma unroll
            for (int r = 0; r < 4; r++) {
                int tg = q64 * 64 + rw + ii * 16 + quad * 4 + r;
                int sg = s64 * 64 + cw + j * 16 + l15;
                float v = macc[ii][j][r];
                mwb[(size_t)tg * T_ + sg] = v;
                mhb[toff(tg, sg, 2048)] = (_Float16)v;
            }
}

// ---------- pass 3a: mean_head partials; block = (tile16, k-quarter) ----------
__global__ __launch_bounds__(256) void k_pass3a(const _Float16* __restrict__ mwh, const _Float16* __restrict__ vt,
                                                _Float16* __restrict__ mhp) {
    __shared__ float red[4][16][64];
    int tid = threadIdx.x, w = tid >> 6, lane = tid & 63, l15 = lane & 15, quad = lane >> 4;
    int blk = blockIdx.x;                          // 1024 = 256 tiles x 4 quarters
    int tile = blk >> 2, q = blk & 3;
    int b = tile >> 7, rtb = tile & 127;
    const _Float16* mb = mwh + (size_t)b * 4194304;
    const _Float16* vb = vt + (size_t)b * 131072;
    int nkc = (rtb * 16 + 47) >> 5;
    int qlo = q * 16;
    int qhi = min(qlo + 16, nkc);
    f32x4 acc[4];
#pragma unroll
    for (int j = 0; j < 4; j++) acc[j] = (f32x4){0.f, 0.f, 0.f, 0.f};
    for (int kc = qlo + w; kc < qhi; kc += 4) {
        f16x8 a = frag_ld(mb, rtb, kc, 64, l15, quad);
#pragma unroll
        for (int j = 0; j < 4; j++) {
            f16x8 bb = frag_ld(vb, j, kc, 64, l15, quad);
            acc[j] = MFMA(a, bb, acc[j]);
        }
    }
#pragma unroll
    for (int j = 0; j < 4; j++)
#pragma unroll
        for (int r = 0; r < 4; r++) red[w][quad * 4 + r][j * 16 + l15] = acc[j][r];
    __syncthreads();
    int r = tid >> 4, dg = tid & 15;
    _Float16* dst = mhp + (size_t)q * 262144;
#pragma unroll
    for (int e = 0; e < 4; e++) {
        int d = dg * 4 + e;
        float s = red[0][r][d] + red[1][r][d] + red[2][r][d] + red[3][r][d];
        dst[toff(tile * 16 + r, d, 64)] = (_Float16)s;
    }
}

// ---------- pass 3b: out = (sum of 4 partials) @ Wo + bo ----------
__global__ __launch_bounds__(256) void k_pass3b(const _Float16* __restrict__ mhp, const _Float16* __restrict__ wot,
                                                const float* __restrict__ bo, float* __restrict__ out0) {
    int bm = blockIdx.x >> 4, bn = blockIdx.x & 15;
    int tid = threadIdx.x, w = tid >> 6, lane = tid & 63, l15 = lane & 15, quad = lane >> 4;
    int rt = bm * 4 + w;
    f16x8 a0[4], a1[4];
#pragma unroll
    for (int q = 0; q < 4; q++) {
        const _Float16* mb = mhp + (size_t)q * 262144;
        a0[q] = frag_ld(mb, rt, 0, 2, l15, quad);
        a1[q] = frag_ld(mb, rt, 1, 2, l15, quad);
    }
    f32x4 acc[4];
#pragma unroll
    for (int j = 0; j < 4; j++) acc[j] = (f32x4){0.f, 0.f, 0.f, 0.f};
#pragma unroll
    for (int j = 0; j < 4; j++) {
        f16x8 b0 = frag_ld(wot, bn * 4 + j, 0, 2, l15, quad);
        f16x8 b1 = frag_ld(wot, bn * 4 + j, 1, 2, l15, quad);
#pragma unroll
        for (int q = 0; q < 4; q++) {
            acc[j] = MFMA(a0[q], b0, acc[j]);
            acc[j] = MFMA(a1[q], b1, acc[j]);
        }
    }
#pragma unroll
    for (int j = 0; j < 4; j++)
#pragma unroll
        for (int r = 0; r < 4; r++) {
            int row = rt * 16 + quad * 4 + r;
            int col = bn * 64 + j * 16 + l15;
            out0[(size_t)row * 1024 + col] = acc[j][r] + bo[col];
        }
}

extern "C" void kernel_launch(void* const* d_in, const int* in_sizes, int n_in,
                              void* d_out, int out_size, void* d_ws, size_t ws_size,
                              hipStream_t stream) {
    const float* x  = (const float*)d_in[0];
    const float* Wq = (const float*)d_in[1];
    const float* bq = (const float*)d_in[2];
    const float* Wk = (const float*)d_in[3];
    const float* bk = (const float*)d_in[4];
    const float* Wv = (const float*)d_in[5];
    const float* bv = (const float*)d_in[6];
    const float* Wo = (const float*)d_in[7];
    const float* bo = (const float*)d_in[8];
    char* ws = (char*)d_ws;
    _Float16* xb    = (_Float16*)(ws + 0);         // 8 MB (dead after vproj)
    _Float16* wqk   = (_Float16*)(ws + 8388608);   // 4 MB (dead after gemm)
    _Float16* wvt   = (_Float16*)(ws + 12582912);  // 128 KB (dead after vproj)
    _Float16* mwh   = (_Float16*)(ws + 0);         // 16 MB overlay
    _Float16* qh    = (_Float16*)(ws + 16777216);  // 8 MB
    _Float16* kh    = (_Float16*)(ws + 25165824);  // 8 MB
    _Float16* vt    = (_Float16*)(ws + 33554432);  // 512 KB
    float*    lstat4= (float*)   (ws + 34078720);  // 1 MB
    _Float16* mhp   = (_Float16*)(ws + 35127296);  // 2 MB (4 partials)
    _Float16* wot   = (_Float16*)(ws + 37224448);  // 128 KB
    float* out0 = (float*)d_out;
    float* mw   = out0 + (size_t)BT_ * H_;

    k_prep    <<<3808, 256, 0, stream>>>(x, Wq, Wk, Wv, Wo, xb, wqk, wvt, wot, mw);
    k_gemm_qk <<<512,  256, 0, stream>>>(xb, wqk, bq, bk, qh, kh);
    k_vproj   <<<256,  256, 0, stream>>>(xb, wvt, bv, vt);
    k_pass1   <<<1024, 256, 0, stream>>>(qh, kh, lstat4);
    k_pass2o  <<<480,  256, 0, stream>>>(qh, kh, lstat4, mw, mwh);
    k_pass2d  <<<96,   256, 0, stream>>>(qh, kh, lstat4, mw, mwh);
    k_pass3a  <<<1024, 256, 0, stream>>>(mwh, vt, mhp);
    k_pass3b  <<<1024, 256, 0, stream>>>(mhp, wot, bo, out0);
}

// Round 6
// 208.879 us; speedup vs baseline: 1.1703x; 1.0521x over previous
//
#include <hip/hip_runtime.h>
#include <hip/hip_bf16.h>

#define B_ 2
#define T_ 2048
#define H_ 1024
#define NH_ 16
#define D_ 64
#define BT_ (B_*T_)
#define SCALE_ 0.125f
#define LOG2E_ 1.4426950408889634f

typedef _Float16 f16x8 __attribute__((ext_vector_type(8)));
typedef float f32x4 __attribute__((ext_vector_type(4)));

#define MFMA(a,b,c) __builtin_amdgcn_mfma_f32_16x16x32_f16((a),(b),(c),0,0,0)
#define EXP2(x) __builtin_amdgcn_exp2f(x)

typedef const __attribute__((address_space(1))) void GV;
typedef __attribute__((address_space(3))) void LV;

// Fragment-tiled layout: matrix [R x C] consumed by MFMA with k-dim = C.
// 16-row tiles, 32-wide k-chunks; chunk block = [quad(k/8)][row%16][k%8] = 512 f16 = 1KB.
__device__ __forceinline__ size_t toff(int r, int c, int C) {
    return (size_t)((r >> 4) * (C >> 5) + (c >> 5)) * 512 + (size_t)(((c & 31) >> 3) * 128 + (r & 15) * 8 + (c & 7));
}
__device__ __forceinline__ f16x8 frag_ld(const _Float16* base, int rt, int kc, int Cc, int l15, int quad) {
    return *(const f16x8*)(base + (size_t)(rt * Cc + kc) * 512 + quad * 128 + l15 * 8);
}

// ---------- prep: cast x, cast Wq/Wk, cast Wv/Wo, zero upper-tri mw — one kernel ----------
__global__ __launch_bounds__(256) void k_prep(const float* __restrict__ x,
                                              const float* __restrict__ Wq, const float* __restrict__ Wk,
                                              const float* __restrict__ Wv, const float* __restrict__ Wo,
                                              _Float16* __restrict__ xb, _Float16* __restrict__ wqk,
                                              _Float16* __restrict__ wvt, _Float16* __restrict__ wot,
                                              float* __restrict__ mw) {
    int blk = blockIdx.x, tid = threadIdx.x;
    if (blk < 2048) {                              // cast x
        int idx = blk * 256 + tid;
        int t = idx >> 7, h0 = (idx & 127) * 8;
        const float* p = x + ((size_t)t << 10) + h0;
        float4 f0 = *(const float4*)p;
        float4 f1 = *(const float4*)(p + 4);
        f16x8 o;
        o[0]=(_Float16)f0.x; o[1]=(_Float16)f0.y; o[2]=(_Float16)f0.z; o[3]=(_Float16)f0.w;
        o[4]=(_Float16)f1.x; o[5]=(_Float16)f1.y; o[6]=(_Float16)f1.z; o[7]=(_Float16)f1.w;
        *(f16x8*)(xb + toff(t, h0, 1024)) = o;
    } else if (blk < 2560) {                       // cast Wq/Wk
        int idx = (blk - 2048) * 256 + tid;
        int head = idx >> 13;
        int rem = idx & 8191;
        int h = rem >> 3;
        int d0 = (rem & 7) * 8;
        const float* pq = Wq + ((size_t)((head << 10) + h)) * 64 + d0;
        const float* pk = Wk + ((size_t)((head << 10) + h)) * 64 + d0;
        float4 q0 = *(const float4*)pq, q1 = *(const float4*)(pq + 4);
        float4 k0 = *(const float4*)pk, k1 = *(const float4*)(pk + 4);
        float qv[8] = {q0.x,q0.y,q0.z,q0.w,q1.x,q1.y,q1.z,q1.w};
        float kv[8] = {k0.x,k0.y,k0.z,k0.w,k1.x,k1.y,k1.z,k1.w};
#pragma unroll
        for (int e = 0; e < 8; e++) {
            int c = head * 64 + d0 + e;
            wqk[toff(c, h, 1024)]        = (_Float16)qv[e];
            wqk[toff(c + 1024, h, 1024)] = (_Float16)kv[e];
        }
    } else if (blk < 2816) {                       // cast Wv/Wo
        int i = (blk - 2560) * 256 + tid;
        int d = i >> 10, h = i & 1023;
        wvt[toff(d, h, 1024)] = (_Float16)Wv[(size_t)h * 64 + d];
        int hh = i >> 6, dd = i & 63;
        wot[toff(hh, dd, 64)] = (_Float16)Wo[(size_t)dd * 1024 + hh];
    } else {                                       // zero upper-tri tiles (992)
        int iz = blk - 2816;
        int b = (iz >= 496) ? 1 : 0;
        int i = iz - b * 496;
        int s64 = (int)((sqrtf(8.f * i + 1.f) + 1.f) * 0.5f);
        if (s64 * (s64 - 1) / 2 > i) s64--;
        if ((s64 + 1) * s64 / 2 <= i) s64++;
        int q64 = i - s64 * (s64 - 1) / 2;         // q64 < s64
        float4 z = {0.f, 0.f, 0.f, 0.f};
#pragma unroll
        for (int it = 0; it < 4; it++) {
            int idx = it * 256 + tid;
            int r = idx >> 4, c4 = idx & 15;
            *(float4*)&mw[(size_t)(b * T_ + q64 * 64 + r) * T_ + s64 * 64 + c4 * 4] = z;
        }
    }
}

// ---------- fused: Q||K GEMM (blocks 0..511, BK=64) + V projection (blocks 512..767) ----------
__global__ __launch_bounds__(256) void k_gemm(const _Float16* __restrict__ xb, const _Float16* __restrict__ wqk,
                                              const float* __restrict__ bq, const float* __restrict__ bk,
                                              const _Float16* __restrict__ wvt, const float* __restrict__ bv,
                                              _Float16* __restrict__ qh, _Float16* __restrict__ kh,
                                              _Float16* __restrict__ vt) {
    __shared__ __align__(16) unsigned char smem[32768];
    _Float16* As = (_Float16*)smem;                // 16 KB
    _Float16* Bs = (_Float16*)(smem + 16384);      // 16 KB
    int tid = threadIdx.x, w = tid >> 6, lane = tid & 63, l15 = lane & 15, quad = lane >> 4;
    if (blockIdx.x >= 512) {                       // ---- vproj path ----
        float (*red)[16][64] = (float(*)[16][64])smem;
        int rt = blockIdx.x - 512;
        f32x4 acc[4];
#pragma unroll
        for (int j = 0; j < 4; j++) acc[j] = (f32x4){0.f, 0.f, 0.f, 0.f};
        for (int q = 0; q < 8; q++) {
            int kc = w * 8 + q;
            f16x8 a = frag_ld(xb, rt, kc, 32, l15, quad);
#pragma unroll
            for (int j = 0; j < 4; j++) {
                f16x8 bb = frag_ld(wvt, j, kc, 32, l15, quad);
                acc[j] = MFMA(a, bb, acc[j]);
            }
        }
#pragma unroll
        for (int j = 0; j < 4; j++)
#pragma unroll
            for (int r = 0; r < 4; r++) red[w][quad * 4 + r][j * 16 + l15] = acc[j][r];
        __syncthreads();
        int r = tid >> 4, dg = tid & 15;
        int b = rt >> 7, tt = (rt & 127) * 16 + r;
        _Float16* vtb = vt + (size_t)b * 131072;
#pragma unroll
        for (int e = 0; e < 4; e++) {
            int d = dg * 4 + e;
            float s = red[0][r][d] + red[1][r][d] + red[2][r][d] + red[3][r][d] + bv[d];
            vtb[toff(d, tt, 2048)] = (_Float16)s;
        }
        return;
    }
    // ---- GEMM path, BK=64 ----
    int bm = blockIdx.x >> 4, bn = blockIdx.x & 15;
    int rowbase = (w >> 1) * 64, colbase = (w & 1) * 64;
    f32x4 acc[4][4];
#pragma unroll
    for (int i = 0; i < 4; i++)
#pragma unroll
        for (int j = 0; j < 4; j++) acc[i][j] = (f32x4){0.f, 0.f, 0.f, 0.f};

    for (int kk = 0; kk < 16; kk++) {
        __syncthreads();
#pragma unroll
        for (int p = 0; p < 4; p++) {
            int c = w * 4 + p;                     // 0..15: rowtile c>>1, k-chunk c&1
            __builtin_amdgcn_global_load_lds((GV*)(xb  + ((size_t)((bm * 8 + (c >> 1)) * 32 + kk * 2 + (c & 1))) * 512 + lane * 8),
                                             (LV*)(As + c * 512 + lane * 8), 16, 0, 0);
            __builtin_amdgcn_global_load_lds((GV*)(wqk + ((size_t)((bn * 8 + (c >> 1)) * 32 + kk * 2 + (c & 1))) * 512 + lane * 8),
                                             (LV*)(Bs + c * 512 + lane * 8), 16, 0, 0);
        }
        __syncthreads();
#pragma unroll
        for (int kc = 0; kc < 2; kc++) {
            f16x8 a[4], bf[4];
#pragma unroll
            for (int i = 0; i < 4; i++) a[i]  = *(const f16x8*)&As[((rowbase >> 4) + i) * 1024 + kc * 512 + quad * 128 + l15 * 8];
#pragma unroll
            for (int j = 0; j < 4; j++) bf[j] = *(const f16x8*)&Bs[((colbase >> 4) + j) * 1024 + kc * 512 + quad * 128 + l15 * 8];
#pragma unroll
            for (int i = 0; i < 4; i++)
#pragma unroll
                for (int j = 0; j < 4; j++) acc[i][j] = MFMA(a[i], bf[j], acc[i][j]);
        }
    }
    __syncthreads();                               // reuse As/Bs for epilogue staging
    int b = (bm * 128) >> 11;
    int t_base = (bm * 128) & 2047;
    int rtbase = (t_base + rowbase) >> 4;
    bool isq = (bn < 8);
    int c2base = isq ? (bn * 128 + colbase) : (bn * 128 + colbase - 1024);
    int n = c2base >> 6;
    _Float16* dst = (isq ? qh : kh) + (size_t)(n * 2 + b) * 131072;
    const float* bias_p = isq ? bq : bk;
    float qs = SCALE_ * LOG2E_;                    // fold softmax scale + log2e into q
    int i2 = lane >> 4, rowrb = lane & 15;
#pragma unroll
    for (int j = 0; j < 4; j++) {
        float bias = bias_p[c2base + j * 16 + l15];
        _Float16* stg = ((j & 1) ? Bs : As) + w * 1024;
#pragma unroll
        for (int i = 0; i < 4; i++)
#pragma unroll
            for (int r = 0; r < 4; r++) {
                float v = acc[i][j][r] + bias;
                if (isq) v *= qs;
                stg[(i * 16 + quad * 4 + r) * 16 + l15] = (_Float16)v;
            }
#pragma unroll
        for (int oct = 0; oct < 2; oct++) {
            f16x8 val = *(const f16x8*)&stg[(i2 * 16 + rowrb) * 16 + oct * 8];
            int dd0 = j * 16 + oct * 8;
            *(f16x8*)(dst + (size_t)((rtbase + i2) * 2 + (dd0 >> 5)) * 512 + ((dd0 & 31) >> 3) * 128 + rowrb * 8) = val;
        }
    }
}

// ---------- pass 1: causal row sum-exp2, 4-way K-split partials ----------
__global__ __launch_bounds__(256) void k_pass1(const _Float16* __restrict__ qh, const _Float16* __restrict__ kh,
                                               float* __restrict__ lstat4) {
    int tid = threadIdx.x, w = tid >> 6, lane = tid & 63, l15 = lane & 15, quad = lane >> 4;
    int blk = blockIdx.x;                          // 1024 blocks
    int n = blk >> 6, b = (blk >> 5) & 1, strip = blk & 31;
    const _Float16* qb = qh + (size_t)(n * 2 + b) * 131072;
    const _Float16* kp = kh + (size_t)(n * 2 + b) * 131072;
    int rt0 = strip * 4;
    f16x8 aq[4][2];
#pragma unroll
    for (int i = 0; i < 4; i++)
#pragma unroll
        for (int kk = 0; kk < 2; kk++) aq[i][kk] = frag_ld(qb, rt0 + i, kk, 2, l15, quad);
    float l[4][4];
#pragma unroll
    for (int i = 0; i < 4; i++)
#pragma unroll
        for (int r = 0; r < 4; r++) l[i][r] = 0.f;
    int st_lo = w * (strip + 1);
    int st_hi = st_lo + strip + 1;
    for (int st = st_lo; st < st_hi; st++) {
        f16x8 c0 = frag_ld(kp, st, 0, 2, l15, quad);
        f16x8 c1 = frag_ld(kp, st, 1, 2, l15, quad);
#pragma unroll
        for (int i = 0; i < 4; i++) {
            if (st > rt0 + i) continue;            // wave-uniform branch
            f32x4 sc = (f32x4){0.f, 0.f, 0.f, 0.f};
            sc = MFMA(aq[i][0], c0, sc);
            sc = MFMA(aq[i][1], c1, sc);
            if (st == rt0 + i) {
#pragma unroll
                for (int r = 0; r < 4; r++)
                    if (l15 <= quad * 4 + r) l[i][r] += EXP2(sc[r]);
            } else {
#pragma unroll
                for (int r = 0; r < 4; r++) l[i][r] += EXP2(sc[r]);
            }
        }
    }
#pragma unroll
    for (int off = 1; off < 16; off <<= 1)
#pragma unroll
        for (int i = 0; i < 4; i++)
#pragma unroll
            for (int r = 0; r < 4; r++) l[i][r] += __shfl_xor(l[i][r], off, 64);
    if (l15 == 0) {
        int base = (n * 2 + b) * 2048 + strip * 64;
#pragma unroll
        for (int i = 0; i < 4; i++)
#pragma unroll
            for (int r = 0; r < 4; r++)
                lstat4[(size_t)(base + i * 16 + quad * 4 + r) * 4 + w] = l[i][r];
    }
}

// ---------- pass 2 (all causal tiles): 128q x 64s, dbuf LDS K-stage, 1 barrier/head ----------
__global__ __launch_bounds__(256) void k_pass2(const _Float16* __restrict__ qh, const _Float16* __restrict__ kh,
                                               const float* __restrict__ lstat4,
                                               float* __restrict__ mw, _Float16* __restrict__ mwh) {
    __shared__ float sl[16][128];                  // 8 KB
    __shared__ __align__(16) _Float16 kst[2][4096];// 16 KB double-buffered K stage (+store transpose)
    int blk = blockIdx.x;                          // 544 = 2b x 272
    int b = (blk >= 272) ? 1 : 0;
    int i0 = blk - 272 * b;
    int i = (i0 & 7) * 34 + (i0 >> 3);             // XCD-banded
    int p = (int)((sqrtf(4.f * i + 1.f) - 1.f) * 0.5f);
    while (p * (p + 1) > i) p--;
    while ((p + 1) * (p + 2) <= i) p++;
    int s64 = i - p * (p + 1);                     // s64 in [0, 2p+2)
    bool masked = (s64 >= 2 * p);                  // diagonal-straddling column
    int tid = threadIdx.x, w = tid >> 6, lane = tid & 63, l15 = lane & 15, quad = lane >> 4;
    for (int ii = tid; ii < 2048; ii += 256) {
        int h = ii >> 7, r = ii & 127;
        const float4 pl = *(const float4*)&lstat4[(size_t)((h * 2 + b) * 2048 + p * 128 + r) * 4];
        sl[h][r] = 0.0625f / (pl.x + pl.y + pl.z + pl.w);
    }
    int rw = w * 32;
    int rt0 = p * 8 + w * 2;                       // q row-tile base (2 per wave)
    int st0 = s64 * 4;                             // k row-tile base (4 per block)
    f32x4 macc[2][4];
#pragma unroll
    for (int ii = 0; ii < 2; ii++)
#pragma unroll
        for (int j = 0; j < 4; j++) macc[ii][j] = (f32x4){0.f, 0.f, 0.f, 0.f};

    // prologue: stage K(head 0), load Q(head 0)
    {
        const _Float16* kp = kh + (size_t)b * 131072;
#pragma unroll
        for (int inst = 0; inst < 2; inst++) {
            int c = inst * 4 + w;
            int gc = (st0 + (c >> 1)) * 2 + (c & 1);
            __builtin_amdgcn_global_load_lds((GV*)(kp + (size_t)gc * 512 + lane * 8),
                                             (LV*)(kst[0] + c * 512 + lane * 8), 16, 0, 0);
        }
    }
    f16x8 An[2][2];
#pragma unroll
    for (int ii = 0; ii < 2; ii++)
#pragma unroll
        for (int kc = 0; kc < 2; kc++) An[ii][kc] = frag_ld(qh + (size_t)b * 131072, rt0 + ii, kc, 2, l15, quad);
    __syncthreads();                               // sl + stage0 + Q0 ready

    for (int n = 0; n < NH_; n++) {
        f16x8 Ac[2][2];
#pragma unroll
        for (int ii = 0; ii < 2; ii++)
#pragma unroll
            for (int kc = 0; kc < 2; kc++) Ac[ii][kc] = An[ii][kc];
        if (n < NH_ - 1) {                         // prefetch head n+1 during compute
            const _Float16* kp = kh + (size_t)((n + 1) * 2 + b) * 131072;
            const _Float16* qb = qh + (size_t)((n + 1) * 2 + b) * 131072;
#pragma unroll
            for (int inst = 0; inst < 2; inst++) {
                int c = inst * 4 + w;
                int gc = (st0 + (c >> 1)) * 2 + (c & 1);
                __builtin_amdgcn_global_load_lds((GV*)(kp + (size_t)gc * 512 + lane * 8),
                                                 (LV*)(kst[(n + 1) & 1] + c * 512 + lane * 8), 16, 0, 0);
            }
#pragma unroll
            for (int ii = 0; ii < 2; ii++)
#pragma unroll
                for (int kc = 0; kc < 2; kc++) An[ii][kc] = frag_ld(qb, rt0 + ii, kc, 2, l15, quad);
        }
        f32x4 slv[2];
#pragma unroll
        for (int ii = 0; ii < 2; ii++) slv[ii] = *(const f32x4*)&sl[n][rw + ii * 16 + quad * 4];
        const _Float16* ks = kst[n & 1];
#pragma unroll
        for (int j = 0; j < 4; j++) {
            f16x8 K0 = *(const f16x8*)&ks[(j * 2 + 0) * 512 + quad * 128 + l15 * 8];
            f16x8 K1 = *(const f16x8*)&ks[(j * 2 + 1) * 512 + quad * 128 + l15 * 8];
#pragma unroll
            for (int ii = 0; ii < 2; ii++) {
                f32x4 sc = (f32x4){0.f, 0.f, 0.f, 0.f};
                sc = MFMA(Ac[ii][0], K0, sc);
                sc = MFMA(Ac[ii][1], K1, sc);
                if (masked) {
                    int sg = s64 * 64 + j * 16 + l15;
#pragma unroll
                    for (int r = 0; r < 4; r++) {
                        int tg = p * 128 + rw + ii * 16 + quad * 4 + r;
                        macc[ii][j][r] += (sg <= tg) ? EXP2(sc[r]) * slv[ii][r] : 0.f;
                    }
                } else {
#pragma unroll
                    for (int r = 0; r < 4; r++) macc[ii][j][r] += EXP2(sc[r]) * slv[ii][r];
                }
            }
        }
        __syncthreads();                           // next stage ready; current reads done
    }
    // fp32 mw store
    float* mwb = mw + (size_t)b * T_ * T_;
#pragma unroll
    for (int ii = 0; ii < 2; ii++)
#pragma unroll
        for (int j = 0; j < 4; j++)
#pragma unroll
            for (int r = 0; r < 4; r++) {
                int tg = p * 128 + rw + ii * 16 + quad * 4 + r;
                int sg = s64 * 64 + j * 16 + l15;
                mwb[(size_t)tg * T_ + sg] = macc[ii][j][r];
            }
    // f16 tiled store via per-wave LDS transpose (2 rounds of 32 cols)
    _Float16* mhb = mwh + (size_t)b * 4194304;
    _Float16* ws16 = kst[0] + w * 1024;            // wave-private 1 KB (post-barrier safe)
    int rowrb = lane & 15, qc = lane >> 4;
#pragma unroll
    for (int cc = 0; cc < 2; cc++) {
#pragma unroll
        for (int ii = 0; ii < 2; ii++)
#pragma unroll
            for (int j2 = 0; j2 < 2; j2++)
#pragma unroll
                for (int r = 0; r < 4; r++) {
                    int clw = j2 * 16 + l15;
                    ws16[ii * 512 + (clw >> 3) * 128 + (quad * 4 + r) * 8 + (clw & 7)] =
                        (_Float16)macc[ii][cc * 2 + j2][r];
                }
#pragma unroll
        for (int ii = 0; ii < 2; ii++) {
            f16x8 val = *(const f16x8*)&ws16[ii * 512 + qc * 128 + rowrb * 8];
            *(f16x8*)(mhb + (size_t)((rt0 + ii) * 64 + (s64 * 2 + cc)) * 512 + qc * 128 + rowrb * 8) = val;
        }
    }
}

// ---------- pass 3a: mean_head partials; block = (tile16, k-quarter) ----------
__global__ __launch_bounds__(256) void k_pass3a(const _Float16* __restrict__ mwh, const _Float16* __restrict__ vt,
                                                _Float16* __restrict__ mhp) {
    __shared__ float red[4][16][64];
    int tid = threadIdx.x, w = tid >> 6, lane = tid & 63, l15 = lane & 15, quad = lane >> 4;
    int blk = blockIdx.x;                          // 1024 = 256 tiles x 4 quarters
    int tile = blk >> 2, q = blk & 3;
    int b = tile >> 7, rtb = tile & 127;
    const _Float16* mb = mwh + (size_t)b * 4194304;
    const _Float16* vb = vt + (size_t)b * 131072;
    int nkc = (rtb * 16 + 47) >> 5;
    int qlo = q * 16;
    int qhi = min(qlo + 16, nkc);
    f32x4 acc[4];
#pragma unroll
    for (int j = 0; j < 4; j++) acc[j] = (f32x4){0.f, 0.f, 0.f, 0.f};
    for (int kc = qlo + w; kc < qhi; kc += 4) {
        f16x8 a = frag_ld(mb, rtb, kc, 64, l15, quad);
#pragma unroll
        for (int j = 0; j < 4; j++) {
            f16x8 bb = frag_ld(vb, j, kc, 64, l15, quad);
            acc[j] = MFMA(a, bb, acc[j]);
        }
    }
#pragma unroll
    for (int j = 0; j < 4; j++)
#pragma unroll
        for (int r = 0; r < 4; r++) red[w][quad * 4 + r][j * 16 + l15] = acc[j][r];
    __syncthreads();
    int r = tid >> 4, dg = tid & 15;
    _Float16* dst = mhp + (size_t)q * 262144;
#pragma unroll
    for (int e = 0; e < 4; e++) {
        int d = dg * 4 + e;
        float s = red[0][r][d] + red[1][r][d] + red[2][r][d] + red[3][r][d];
        dst[toff(tile * 16 + r, d, 64)] = (_Float16)s;
    }
}

// ---------- pass 3b: out = (sum of 4 partials) @ Wo + bo ----------
__global__ __launch_bounds__(256) void k_pass3b(const _Float16* __restrict__ mhp, const _Float16* __restrict__ wot,
                                                const float* __restrict__ bo, float* __restrict__ out0) {
    int bm = blockIdx.x >> 4, bn = blockIdx.x & 15;
    int tid = threadIdx.x, w = tid >> 6, lane = tid & 63, l15 = lane & 15, quad = lane >> 4;
    int rt = bm * 4 + w;
    f16x8 a0[4], a1[4];
#pragma unroll
    for (int q = 0; q < 4; q++) {
        const _Float16* mb = mhp + (size_t)q * 262144;
        a0[q] = frag_ld(mb, rt, 0, 2, l15, quad);
        a1[q] = frag_ld(mb, rt, 1, 2, l15, quad);
    }
    f32x4 acc[4];
#pragma unroll
    for (int j = 0; j < 4; j++) acc[j] = (f32x4){0.f, 0.f, 0.f, 0.f};
#pragma unroll
    for (int j = 0; j < 4; j++) {
        f16x8 b0 = frag_ld(wot, bn * 4 + j, 0, 2, l15, quad);
        f16x8 b1 = frag_ld(wot, bn * 4 + j, 1, 2, l15, quad);
#pragma unroll
        for (int q = 0; q < 4; q++) {
            acc[j] = MFMA(a0[q], b0, acc[j]);
            acc[j] = MFMA(a1[q], b1, acc[j]);
        }
    }
#pragma unroll
    for (int j = 0; j < 4; j++)
#pragma unroll
        for (int r = 0; r < 4; r++) {
            int row = rt * 16 + quad * 4 + r;
            int col = bn * 64 + j * 16 + l15;
            out0[(size_t)row * 1024 + col] = acc[j][r] + bo[col];
        }
}

extern "C" void kernel_launch(void* const* d_in, const int* in_sizes, int n_in,
                              void* d_out, int out_size, void* d_ws, size_t ws_size,
                              hipStream_t stream) {
    const float* x  = (const float*)d_in[0];
    const float* Wq = (const float*)d_in[1];
    const float* bq = (const float*)d_in[2];
    const float* Wk = (const float*)d_in[3];
    const float* bk = (const float*)d_in[4];
    const float* Wv = (const float*)d_in[5];
    const float* bv = (const float*)d_in[6];
    const float* Wo = (const float*)d_in[7];
    const float* bo = (const float*)d_in[8];
    char* ws = (char*)d_ws;
    _Float16* xb    = (_Float16*)(ws + 0);         // 8 MB (dead after gemm/vproj)
    _Float16* wqk   = (_Float16*)(ws + 8388608);   // 4 MB (dead after gemm)
    _Float16* wvt   = (_Float16*)(ws + 12582912);  // 128 KB (dead after vproj)
    _Float16* mwh   = (_Float16*)(ws + 0);         // 16 MB overlay
    _Float16* qh    = (_Float16*)(ws + 16777216);  // 8 MB
    _Float16* kh    = (_Float16*)(ws + 25165824);  // 8 MB
    _Float16* vt    = (_Float16*)(ws + 33554432);  // 512 KB
    float*    lstat4= (float*)   (ws + 34078720);  // 1 MB
    _Float16* mhp   = (_Float16*)(ws + 35127296);  // 2 MB (4 partials)
    _Float16* wot   = (_Float16*)(ws + 37224448);  // 128 KB
    float* out0 = (float*)d_out;
    float* mw   = out0 + (size_t)BT_ * H_;

    k_prep   <<<3808, 256, 0, stream>>>(x, Wq, Wk, Wv, Wo, xb, wqk, wvt, wot, mw);
    k_gemm   <<<768,  256, 0, stream>>>(xb, wqk, bq, bk, wvt, bv, qh, kh, vt);
    k_pass1  <<<1024, 256, 0, stream>>>(qh, kh, lstat4);
    k_pass2  <<<544,  256, 0, stream>>>(qh, kh, lstat4, mw, mwh);
    k_pass3a <<<1024, 256, 0, stream>>>(mwh, vt, mhp);
    k_pass3b <<<1024, 256, 0, stream>>>(mhp, wot, bo, out0);
}

// Round 7
// 206.082 us; speedup vs baseline: 1.1862x; 1.0136x over previous
//
#include <hip/hip_runtime.h>
#include <hip/hip_bf16.h>

#define B_ 2
#define T_ 2048
#define H_ 1024
#define NH_ 16
#define D_ 64
#define BT_ (B_*T_)
#define SCALE_ 0.125f
#define LOG2E_ 1.4426950408889634f

typedef _Float16 f16x8 __attribute__((ext_vector_type(8)));
typedef float f32x4 __attribute__((ext_vector_type(4)));

#define MFMA(a,b,c) __builtin_amdgcn_mfma_f32_16x16x32_f16((a),(b),(c),0,0,0)
#define EXP2(x) __builtin_amdgcn_exp2f(x)

typedef const __attribute__((address_space(1))) void GV;
typedef __attribute__((address_space(3))) void LV;

// Fragment-tiled layout: matrix [R x C] consumed by MFMA with k-dim = C.
// 16-row tiles, 32-wide k-chunks; chunk block = [quad(k/8)][row%16][k%8] = 512 f16 = 1KB.
__device__ __forceinline__ size_t toff(int r, int c, int C) {
    return (size_t)((r >> 4) * (C >> 5) + (c >> 5)) * 512 + (size_t)(((c & 31) >> 3) * 128 + (r & 15) * 8 + (c & 7));
}
__device__ __forceinline__ f16x8 frag_ld(const _Float16* base, int rt, int kc, int Cc, int l15, int quad) {
    return *(const f16x8*)(base + (size_t)(rt * Cc + kc) * 512 + quad * 128 + l15 * 8);
}

// ---------- prep: cast x, cast Wq/Wk, cast Wv/Wo, zero upper-tri mw — one kernel ----------
__global__ __launch_bounds__(256) void k_prep(const float* __restrict__ x,
                                              const float* __restrict__ Wq, const float* __restrict__ Wk,
                                              const float* __restrict__ Wv, const float* __restrict__ Wo,
                                              _Float16* __restrict__ xb, _Float16* __restrict__ wqk,
                                              _Float16* __restrict__ wvt, _Float16* __restrict__ wot,
                                              float* __restrict__ mw) {
    int blk = blockIdx.x, tid = threadIdx.x;
    if (blk < 2048) {                              // cast x
        int idx = blk * 256 + tid;
        int t = idx >> 7, h0 = (idx & 127) * 8;
        const float* p = x + ((size_t)t << 10) + h0;
        float4 f0 = *(const float4*)p;
        float4 f1 = *(const float4*)(p + 4);
        f16x8 o;
        o[0]=(_Float16)f0.x; o[1]=(_Float16)f0.y; o[2]=(_Float16)f0.z; o[3]=(_Float16)f0.w;
        o[4]=(_Float16)f1.x; o[5]=(_Float16)f1.y; o[6]=(_Float16)f1.z; o[7]=(_Float16)f1.w;
        *(f16x8*)(xb + toff(t, h0, 1024)) = o;
    } else if (blk < 2560) {                       // cast Wq/Wk
        int idx = (blk - 2048) * 256 + tid;
        int head = idx >> 13;
        int rem = idx & 8191;
        int h = rem >> 3;
        int d0 = (rem & 7) * 8;
        const float* pq = Wq + ((size_t)((head << 10) + h)) * 64 + d0;
        const float* pk = Wk + ((size_t)((head << 10) + h)) * 64 + d0;
        float4 q0 = *(const float4*)pq, q1 = *(const float4*)(pq + 4);
        float4 k0 = *(const float4*)pk, k1 = *(const float4*)(pk + 4);
        float qv[8] = {q0.x,q0.y,q0.z,q0.w,q1.x,q1.y,q1.z,q1.w};
        float kv[8] = {k0.x,k0.y,k0.z,k0.w,k1.x,k1.y,k1.z,k1.w};
#pragma unroll
        for (int e = 0; e < 8; e++) {
            int c = head * 64 + d0 + e;
            wqk[toff(c, h, 1024)]        = (_Float16)qv[e];
            wqk[toff(c + 1024, h, 1024)] = (_Float16)kv[e];
        }
    } else if (blk < 2816) {                       // cast Wv/Wo
        int i = (blk - 2560) * 256 + tid;
        int d = i >> 10, h = i & 1023;
        wvt[toff(d, h, 1024)] = (_Float16)Wv[(size_t)h * 64 + d];
        int hh = i >> 6, dd = i & 63;
        wot[toff(hh, dd, 64)] = (_Float16)Wo[(size_t)dd * 1024 + hh];
    } else {                                       // zero upper-tri tiles (992)
        int iz = blk - 2816;
        int b = (iz >= 496) ? 1 : 0;
        int i = iz - b * 496;
        int s64 = (int)((sqrtf(8.f * i + 1.f) + 1.f) * 0.5f);
        if (s64 * (s64 - 1) / 2 > i) s64--;
        if ((s64 + 1) * s64 / 2 <= i) s64++;
        int q64 = i - s64 * (s64 - 1) / 2;         // q64 < s64
        float4 z = {0.f, 0.f, 0.f, 0.f};
#pragma unroll
        for (int it = 0; it < 4; it++) {
            int idx = it * 256 + tid;
            int r = idx >> 4, c4 = idx & 15;
            *(float4*)&mw[(size_t)(b * T_ + q64 * 64 + r) * T_ + s64 * 64 + c4 * 4] = z;
        }
    }
}

// ---------- fused: Q||K GEMM (blocks 0..511, BK=64) + V projection (blocks 512..767) ----------
__global__ __launch_bounds__(256) void k_gemm(const _Float16* __restrict__ xb, const _Float16* __restrict__ wqk,
                                              const float* __restrict__ bq, const float* __restrict__ bk,
                                              const _Float16* __restrict__ wvt, const float* __restrict__ bv,
                                              _Float16* __restrict__ qh, _Float16* __restrict__ kh,
                                              _Float16* __restrict__ vt) {
    __shared__ __align__(16) unsigned char smem[32768];
    _Float16* As = (_Float16*)smem;                // 16 KB
    _Float16* Bs = (_Float16*)(smem + 16384);      // 16 KB
    int tid = threadIdx.x, w = tid >> 6, lane = tid & 63, l15 = lane & 15, quad = lane >> 4;
    if (blockIdx.x >= 512) {                       // ---- vproj path ----
        float (*red)[16][64] = (float(*)[16][64])smem;
        int rt = blockIdx.x - 512;
        f32x4 acc[4];
#pragma unroll
        for (int j = 0; j < 4; j++) acc[j] = (f32x4){0.f, 0.f, 0.f, 0.f};
        for (int q = 0; q < 8; q++) {
            int kc = w * 8 + q;
            f16x8 a = frag_ld(xb, rt, kc, 32, l15, quad);
#pragma unroll
            for (int j = 0; j < 4; j++) {
                f16x8 bb = frag_ld(wvt, j, kc, 32, l15, quad);
                acc[j] = MFMA(a, bb, acc[j]);
            }
        }
#pragma unroll
        for (int j = 0; j < 4; j++)
#pragma unroll
            for (int r = 0; r < 4; r++) red[w][quad * 4 + r][j * 16 + l15] = acc[j][r];
        __syncthreads();
        int r = tid >> 4, dg = tid & 15;
        int b = rt >> 7, tt = (rt & 127) * 16 + r;
        _Float16* vtb = vt + (size_t)b * 131072;
#pragma unroll
        for (int e = 0; e < 4; e++) {
            int d = dg * 4 + e;
            float s = red[0][r][d] + red[1][r][d] + red[2][r][d] + red[3][r][d] + bv[d];
            vtb[toff(d, tt, 2048)] = (_Float16)s;
        }
        return;
    }
    // ---- GEMM path, BK=64 ----
    int bm = blockIdx.x >> 4, bn = blockIdx.x & 15;
    int rowbase = (w >> 1) * 64, colbase = (w & 1) * 64;
    f32x4 acc[4][4];
#pragma unroll
    for (int i = 0; i < 4; i++)
#pragma unroll
        for (int j = 0; j < 4; j++) acc[i][j] = (f32x4){0.f, 0.f, 0.f, 0.f};

    for (int kk = 0; kk < 16; kk++) {
        __syncthreads();
#pragma unroll
        for (int p = 0; p < 4; p++) {
            int c = w * 4 + p;                     // 0..15: rowtile c>>1, k-chunk c&1
            __builtin_amdgcn_global_load_lds((GV*)(xb  + ((size_t)((bm * 8 + (c >> 1)) * 32 + kk * 2 + (c & 1))) * 512 + lane * 8),
                                             (LV*)(As + c * 512 + lane * 8), 16, 0, 0);
            __builtin_amdgcn_global_load_lds((GV*)(wqk + ((size_t)((bn * 8 + (c >> 1)) * 32 + kk * 2 + (c & 1))) * 512 + lane * 8),
                                             (LV*)(Bs + c * 512 + lane * 8), 16, 0, 0);
        }
        __syncthreads();
#pragma unroll
        for (int kc = 0; kc < 2; kc++) {
            f16x8 a[4], bf[4];
#pragma unroll
            for (int i = 0; i < 4; i++) a[i]  = *(const f16x8*)&As[((rowbase >> 4) + i) * 1024 + kc * 512 + quad * 128 + l15 * 8];
#pragma unroll
            for (int j = 0; j < 4; j++) bf[j] = *(const f16x8*)&Bs[((colbase >> 4) + j) * 1024 + kc * 512 + quad * 128 + l15 * 8];
#pragma unroll
            for (int i = 0; i < 4; i++)
#pragma unroll
                for (int j = 0; j < 4; j++) acc[i][j] = MFMA(a[i], bf[j], acc[i][j]);
        }
    }
    __syncthreads();                               // reuse As/Bs for epilogue staging
    int b = (bm * 128) >> 11;
    int t_base = (bm * 128) & 2047;
    int rtbase = (t_base + rowbase) >> 4;
    bool isq = (bn < 8);
    int c2base = isq ? (bn * 128 + colbase) : (bn * 128 + colbase - 1024);
    int n = c2base >> 6;
    _Float16* dst = (isq ? qh : kh) + (size_t)(n * 2 + b) * 131072;
    const float* bias_p = isq ? bq : bk;
    float qs = SCALE_ * LOG2E_;                    // fold softmax scale + log2e into q
    int i2 = lane >> 4, rowrb = lane & 15;
#pragma unroll
    for (int j = 0; j < 4; j++) {
        float bias = bias_p[c2base + j * 16 + l15];
        _Float16* stg = ((j & 1) ? Bs : As) + w * 1024;
#pragma unroll
        for (int i = 0; i < 4; i++)
#pragma unroll
            for (int r = 0; r < 4; r++) {
                float v = acc[i][j][r] + bias;
                if (isq) v *= qs;
                stg[(i * 16 + quad * 4 + r) * 16 + l15] = (_Float16)v;
            }
#pragma unroll
        for (int oct = 0; oct < 2; oct++) {
            f16x8 val = *(const f16x8*)&stg[(i2 * 16 + rowrb) * 16 + oct * 8];
            int dd0 = j * 16 + oct * 8;
            *(f16x8*)(dst + (size_t)((rtbase + i2) * 2 + (dd0 >> 5)) * 512 + ((dd0 & 31) >> 3) * 128 + rowrb * 8) = val;
        }
    }
}

// ---------- pass 1: causal row sum-exp2, 4-way K-split partials ----------
__global__ __launch_bounds__(256) void k_pass1(const _Float16* __restrict__ qh, const _Float16* __restrict__ kh,
                                               float* __restrict__ lstat4) {
    int tid = threadIdx.x, w = tid >> 6, lane = tid & 63, l15 = lane & 15, quad = lane >> 4;
    int blk = blockIdx.x;                          // 1024 blocks
    int n = blk >> 6, b = (blk >> 5) & 1, strip = blk & 31;
    const _Float16* qb = qh + (size_t)(n * 2 + b) * 131072;
    const _Float16* kp = kh + (size_t)(n * 2 + b) * 131072;
    int rt0 = strip * 4;
    f16x8 aq[4][2];
#pragma unroll
    for (int i = 0; i < 4; i++)
#pragma unroll
        for (int kk = 0; kk < 2; kk++) aq[i][kk] = frag_ld(qb, rt0 + i, kk, 2, l15, quad);
    float l[4][4];
#pragma unroll
    for (int i = 0; i < 4; i++)
#pragma unroll
        for (int r = 0; r < 4; r++) l[i][r] = 0.f;
    int st_lo = w * (strip + 1);
    int st_hi = st_lo + strip + 1;
    for (int st = st_lo; st < st_hi; st++) {
        f16x8 c0 = frag_ld(kp, st, 0, 2, l15, quad);
        f16x8 c1 = frag_ld(kp, st, 1, 2, l15, quad);
#pragma unroll
        for (int i = 0; i < 4; i++) {
            if (st > rt0 + i) continue;            // wave-uniform branch
            f32x4 sc = (f32x4){0.f, 0.f, 0.f, 0.f};
            sc = MFMA(aq[i][0], c0, sc);
            sc = MFMA(aq[i][1], c1, sc);
            if (st == rt0 + i) {
#pragma unroll
                for (int r = 0; r < 4; r++)
                    if (l15 <= quad * 4 + r) l[i][r] += EXP2(sc[r]);
            } else {
#pragma unroll
                for (int r = 0; r < 4; r++) l[i][r] += EXP2(sc[r]);
            }
        }
    }
#pragma unroll
    for (int off = 1; off < 16; off <<= 1)
#pragma unroll
        for (int i = 0; i < 4; i++)
#pragma unroll
            for (int r = 0; r < 4; r++) l[i][r] += __shfl_xor(l[i][r], off, 64);
    if (l15 == 0) {
        int base = (n * 2 + b) * 2048 + strip * 64;
#pragma unroll
        for (int i = 0; i < 4; i++)
#pragma unroll
            for (int r = 0; r < 4; r++)
                lstat4[(size_t)(base + i * 16 + quad * 4 + r) * 4 + w] = l[i][r];
    }
}

// ---------- pass 2 (all causal tiles): 128q x 64s, dbuf LDS K-stage, 1 barrier/head ----------
// __launch_bounds__(256,4): force VGPR<=128 -> 4 waves/SIMD (occupancy was the round-6 binder)
__global__ __launch_bounds__(256, 4) void k_pass2(const _Float16* __restrict__ qh, const _Float16* __restrict__ kh,
                                                  const float* __restrict__ lstat4,
                                                  float* __restrict__ mw, _Float16* __restrict__ mwh) {
    __shared__ float sl[16][128];                  // 8 KB
    __shared__ __align__(16) _Float16 kst[2][4096];// 16 KB double-buffered K stage (+store transpose)
    int blk = blockIdx.x;                          // 544 = 2b x 272
    int b = (blk >= 272) ? 1 : 0;
    int i0 = blk - 272 * b;
    int i = (i0 & 7) * 34 + (i0 >> 3);             // XCD-banded
    int p = (int)((sqrtf(4.f * i + 1.f) - 1.f) * 0.5f);
    while (p * (p + 1) > i) p--;
    while ((p + 1) * (p + 2) <= i) p++;
    int s64 = i - p * (p + 1);                     // s64 in [0, 2p+2)
    bool masked = (s64 >= 2 * p);                  // diagonal-straddling column
    int tid = threadIdx.x, w = tid >> 6, lane = tid & 63, l15 = lane & 15, quad = lane >> 4;
    for (int ii = tid; ii < 2048; ii += 256) {
        int h = ii >> 7, r = ii & 127;
        const float4 pl = *(const float4*)&lstat4[(size_t)((h * 2 + b) * 2048 + p * 128 + r) * 4];
        sl[h][r] = 0.0625f / (pl.x + pl.y + pl.z + pl.w);
    }
    int rw = w * 32;
    int rt0 = p * 8 + w * 2;                       // q row-tile base (2 per wave)
    int st0 = s64 * 4;                             // k row-tile base (4 per block)
    f32x4 macc[2][4];
#pragma unroll
    for (int ii = 0; ii < 2; ii++)
#pragma unroll
        for (int j = 0; j < 4; j++) macc[ii][j] = (f32x4){0.f, 0.f, 0.f, 0.f};

    // prologue: stage K(head 0)
    {
        const _Float16* kp = kh + (size_t)b * 131072;
#pragma unroll
        for (int inst = 0; inst < 2; inst++) {
            int c = inst * 4 + w;
            int gc = (st0 + (c >> 1)) * 2 + (c & 1);
            __builtin_amdgcn_global_load_lds((GV*)(kp + (size_t)gc * 512 + lane * 8),
                                             (LV*)(kst[0] + c * 512 + lane * 8), 16, 0, 0);
        }
    }
    __syncthreads();                               // sl + stage0 ready

    for (int n = 0; n < NH_; n++) {
        if (n < NH_ - 1) {                         // prefetch head n+1's K during compute
            const _Float16* kp = kh + (size_t)((n + 1) * 2 + b) * 131072;
#pragma unroll
            for (int inst = 0; inst < 2; inst++) {
                int c = inst * 4 + w;
                int gc = (st0 + (c >> 1)) * 2 + (c & 1);
                __builtin_amdgcn_global_load_lds((GV*)(kp + (size_t)gc * 512 + lane * 8),
                                                 (LV*)(kst[(n + 1) & 1] + c * 512 + lane * 8), 16, 0, 0);
            }
        }
        // Q frags for head n (issued early; latency overlaps the kst ds_reads below)
        const _Float16* qb = qh + (size_t)(n * 2 + b) * 131072;
        f16x8 A[2][2];
#pragma unroll
        for (int ii = 0; ii < 2; ii++)
#pragma unroll
            for (int kc = 0; kc < 2; kc++) A[ii][kc] = frag_ld(qb, rt0 + ii, kc, 2, l15, quad);
        f32x4 slv[2];
#pragma unroll
        for (int ii = 0; ii < 2; ii++) slv[ii] = *(const f32x4*)&sl[n][rw + ii * 16 + quad * 4];
        const _Float16* ks = kst[n & 1];
#pragma unroll
        for (int j = 0; j < 4; j++) {
            f16x8 K0 = *(const f16x8*)&ks[(j * 2 + 0) * 512 + quad * 128 + l15 * 8];
            f16x8 K1 = *(const f16x8*)&ks[(j * 2 + 1) * 512 + quad * 128 + l15 * 8];
#pragma unroll
            for (int ii = 0; ii < 2; ii++) {
                f32x4 sc = (f32x4){0.f, 0.f, 0.f, 0.f};
                sc = MFMA(A[ii][0], K0, sc);
                sc = MFMA(A[ii][1], K1, sc);
                if (masked) {
                    int sg = s64 * 64 + j * 16 + l15;
#pragma unroll
                    for (int r = 0; r < 4; r++) {
                        int tg = p * 128 + rw + ii * 16 + quad * 4 + r;
                        macc[ii][j][r] += (sg <= tg) ? EXP2(sc[r]) * slv[ii][r] : 0.f;
                    }
                } else {
#pragma unroll
                    for (int r = 0; r < 4; r++) macc[ii][j][r] += EXP2(sc[r]) * slv[ii][r];
                }
            }
        }
        __syncthreads();                           // next stage ready; current reads done
    }
    // fp32 mw store
    float* mwb = mw + (size_t)b * T_ * T_;
#pragma unroll
    for (int ii = 0; ii < 2; ii++)
#pragma unroll
        for (int j = 0; j < 4; j++)
#pragma unroll
            for (int r = 0; r < 4; r++) {
                int tg = p * 128 + rw + ii * 16 + quad * 4 + r;
                int sg = s64 * 64 + j * 16 + l15;
                mwb[(size_t)tg * T_ + sg] = macc[ii][j][r];
            }
    // f16 tiled store via per-wave LDS transpose (2 rounds of 32 cols)
    _Float16* mhb = mwh + (size_t)b * 4194304;
    _Float16* ws16 = kst[0] + w * 1024;            // wave-private 1 KB (post-barrier safe)
    int rowrb = lane & 15, qc = lane >> 4;
#pragma unroll
    for (int cc = 0; cc < 2; cc++) {
#pragma unroll
        for (int ii = 0; ii < 2; ii++)
#pragma unroll
            for (int j2 = 0; j2 < 2; j2++)
#pragma unroll
                for (int r = 0; r < 4; r++) {
                    int clw = j2 * 16 + l15;
                    ws16[ii * 512 + (clw >> 3) * 128 + (quad * 4 + r) * 8 + (clw & 7)] =
                        (_Float16)macc[ii][cc * 2 + j2][r];
                }
#pragma unroll
        for (int ii = 0; ii < 2; ii++) {
            f16x8 val = *(const f16x8*)&ws16[ii * 512 + qc * 128 + rowrb * 8];
            *(f16x8*)(mhb + (size_t)((rt0 + ii) * 64 + (s64 * 2 + cc)) * 512 + qc * 128 + rowrb * 8) = val;
        }
    }
}

// ---------- pass 3a: mean_head partials; block = (tile16, k-quarter) ----------
__global__ __launch_bounds__(256) void k_pass3a(const _Float16* __restrict__ mwh, const _Float16* __restrict__ vt,
                                                _Float16* __restrict__ mhp) {
    __shared__ float red[4][16][64];
    int tid = threadIdx.x, w = tid >> 6, lane = tid & 63, l15 = lane & 15, quad = lane >> 4;
    int blk = blockIdx.x;                          // 1024 = 256 tiles x 4 quarters
    int tile = blk >> 2, q = blk & 3;
    int b = tile >> 7, rtb = tile & 127;
    const _Float16* mb = mwh + (size_t)b * 4194304;
    const _Float16* vb = vt + (size_t)b * 131072;
    int nkc = (rtb * 16 + 47) >> 5;
    int qlo = q * 16;
    int qhi = min(qlo + 16, nkc);
    f32x4 acc[4];
#pragma unroll
    for (int j = 0; j < 4; j++) acc[j] = (f32x4){0.f, 0.f, 0.f, 0.f};
    for (int kc = qlo + w; kc < qhi; kc += 4) {
        f16x8 a = frag_ld(mb, rtb, kc, 64, l15, quad);
#pragma unroll
        for (int j = 0; j < 4; j++) {
            f16x8 bb = frag_ld(vb, j, kc, 64, l15, quad);
            acc[j] = MFMA(a, bb, acc[j]);
        }
    }
#pragma unroll
    for (int j = 0; j < 4; j++)
#pragma unroll
        for (int r = 0; r < 4; r++) red[w][quad * 4 + r][j * 16 + l15] = acc[j][r];
    __syncthreads();
    int r = tid >> 4, dg = tid & 15;
    _Float16* dst = mhp + (size_t)q * 262144;
#pragma unroll
    for (int e = 0; e < 4; e++) {
        int d = dg * 4 + e;
        float s = red[0][r][d] + red[1][r][d] + red[2][r][d] + red[3][r][d];
        dst[toff(tile * 16 + r, d, 64)] = (_Float16)s;
    }
}

// ---------- pass 3b: out = (sum of 4 partials) @ Wo + bo ----------
__global__ __launch_bounds__(256) void k_pass3b(const _Float16* __restrict__ mhp, const _Float16* __restrict__ wot,
                                                const float* __restrict__ bo, float* __restrict__ out0) {
    int bm = blockIdx.x >> 4, bn = blockIdx.x & 15;
    int tid = threadIdx.x, w = tid >> 6, lane = tid & 63, l15 = lane & 15, quad = lane >> 4;
    int rt = bm * 4 + w;
    f16x8 a0[4], a1[4];
#pragma unroll
    for (int q = 0; q < 4; q++) {
        const _Float16* mb = mhp + (size_t)q * 262144;
        a0[q] = frag_ld(mb, rt, 0, 2, l15, quad);
        a1[q] = frag_ld(mb, rt, 1, 2, l15, quad);
    }
    f32x4 acc[4];
#pragma unroll
    for (int j = 0; j < 4; j++) acc[j] = (f32x4){0.f, 0.f, 0.f, 0.f};
#pragma unroll
    for (int j = 0; j < 4; j++) {
        f16x8 b0 = frag_ld(wot, bn * 4 + j, 0, 2, l15, quad);
        f16x8 b1 = frag_ld(wot, bn * 4 + j, 1, 2, l15, quad);
#pragma unroll
        for (int q = 0; q < 4; q++) {
            acc[j] = MFMA(a0[q], b0, acc[j]);
            acc[j] = MFMA(a1[q], b1, acc[j]);
        }
    }
#pragma unroll
    for (int j = 0; j < 4; j++)
#pragma unroll
        for (int r = 0; r < 4; r++) {
            int row = rt * 16 + quad * 4 + r;
            int col = bn * 64 + j * 16 + l15;
            out0[(size_t)row * 1024 + col] = acc[j][r] + bo[col];
        }
}

extern "C" void kernel_launch(void* const* d_in, const int* in_sizes, int n_in,
                              void* d_out, int out_size, void* d_ws, size_t ws_size,
                              hipStream_t stream) {
    const float* x  = (const float*)d_in[0];
    const float* Wq = (const float*)d_in[1];
    const float* bq = (const float*)d_in[2];
    const float* Wk = (const float*)d_in[3];
    const float* bk = (const float*)d_in[4];
    const float* Wv = (const float*)d_in[5];
    const float* bv = (const float*)d_in[6];
    const float* Wo = (const float*)d_in[7];
    const float* bo = (const float*)d_in[8];
    char* ws = (char*)d_ws;
    _Float16* xb    = (_Float16*)(ws + 0);         // 8 MB (dead after gemm/vproj)
    _Float16* wqk   = (_Float16*)(ws + 8388608);   // 4 MB (dead after gemm)
    _Float16* wvt   = (_Float16*)(ws + 12582912);  // 128 KB (dead after vproj)
    _Float16* mwh   = (_Float16*)(ws + 0);         // 16 MB overlay
    _Float16* qh    = (_Float16*)(ws + 16777216);  // 8 MB
    _Float16* kh    = (_Float16*)(ws + 25165824);  // 8 MB
    _Float16* vt    = (_Float16*)(ws + 33554432);  // 512 KB
    float*    lstat4= (float*)   (ws + 34078720);  // 1 MB
    _Float16* mhp   = (_Float16*)(ws + 35127296);  // 2 MB (4 partials)
    _Float16* wot   = (_Float16*)(ws + 37224448);  // 128 KB
    float* out0 = (float*)d_out;
    float* mw   = out0 + (size_t)BT_ * H_;

    k_prep   <<<3808, 256, 0, stream>>>(x, Wq, Wk, Wv, Wo, xb, wqk, wvt, wot, mw);
    k_gemm   <<<768,  256, 0, stream>>>(xb, wqk, bq, bk, wvt, bv, qh, kh, vt);
    k_pass1  <<<1024, 256, 0, stream>>>(qh, kh, lstat4);
    k_pass2  <<<544,  256, 0, stream>>>(qh, kh, lstat4, mw, mwh);
    k_pass3a <<<1024, 256, 0, stream>>>(mwh, vt, mhp);
    k_pass3b <<<1024, 256, 0, stream>>>(mhp, wot, bo, out0);
}

// Round 8
// 196.857 us; speedup vs baseline: 1.2418x; 1.0469x over previous
//
#include <hip/hip_runtime.h>
#include <hip/hip_bf16.h>

#define B_ 2
#define T_ 2048
#define H_ 1024
#define NH_ 16
#define D_ 64
#define BT_ (B_*T_)
#define SCALE_ 0.125f
#define LOG2E_ 1.4426950408889634f

typedef _Float16 f16x8 __attribute__((ext_vector_type(8)));
typedef float f32x4 __attribute__((ext_vector_type(4)));

#define MFMA(a,b,c) __builtin_amdgcn_mfma_f32_16x16x32_f16((a),(b),(c),0,0,0)
#define EXP2(x) __builtin_amdgcn_exp2f(x)

typedef const __attribute__((address_space(1))) void GV;
typedef __attribute__((address_space(3))) void LV;

// Fragment-tiled layout: matrix [R x C] consumed by MFMA with k-dim = C.
// 16-row tiles, 32-wide k-chunks; chunk block = [quad(k/8)][row%16][k%8] = 512 f16 = 1KB.
__device__ __forceinline__ size_t toff(int r, int c, int C) {
    return (size_t)((r >> 4) * (C >> 5) + (c >> 5)) * 512 + (size_t)(((c & 31) >> 3) * 128 + (r & 15) * 8 + (c & 7));
}
__device__ __forceinline__ f16x8 frag_ld(const _Float16* base, int rt, int kc, int Cc, int l15, int quad) {
    return *(const f16x8*)(base + (size_t)(rt * Cc + kc) * 512 + quad * 128 + l15 * 8);
}

// ---------- prep: cast x, cast Wq/Wk, cast Wv/Wo, zero upper-tri mw — one kernel ----------
__global__ __launch_bounds__(256) void k_prep(const float* __restrict__ x,
                                              const float* __restrict__ Wq, const float* __restrict__ Wk,
                                              const float* __restrict__ Wv, const float* __restrict__ Wo,
                                              _Float16* __restrict__ xb, _Float16* __restrict__ wqk,
                                              _Float16* __restrict__ wvt, _Float16* __restrict__ wot,
                                              float* __restrict__ mw) {
    int blk = blockIdx.x, tid = threadIdx.x;
    if (blk < 2048) {                              // cast x
        int idx = blk * 256 + tid;
        int t = idx >> 7, h0 = (idx & 127) * 8;
        const float* p = x + ((size_t)t << 10) + h0;
        float4 f0 = *(const float4*)p;
        float4 f1 = *(const float4*)(p + 4);
        f16x8 o;
        o[0]=(_Float16)f0.x; o[1]=(_Float16)f0.y; o[2]=(_Float16)f0.z; o[3]=(_Float16)f0.w;
        o[4]=(_Float16)f1.x; o[5]=(_Float16)f1.y; o[6]=(_Float16)f1.z; o[7]=(_Float16)f1.w;
        *(f16x8*)(xb + toff(t, h0, 1024)) = o;
    } else if (blk < 2560) {                       // cast Wq/Wk
        int idx = (blk - 2048) * 256 + tid;
        int head = idx >> 13;
        int rem = idx & 8191;
        int h = rem >> 3;
        int d0 = (rem & 7) * 8;
        const float* pq = Wq + ((size_t)((head << 10) + h)) * 64 + d0;
        const float* pk = Wk + ((size_t)((head << 10) + h)) * 64 + d0;
        float4 q0 = *(const float4*)pq, q1 = *(const float4*)(pq + 4);
        float4 k0 = *(const float4*)pk, k1 = *(const float4*)(pk + 4);
        float qv[8] = {q0.x,q0.y,q0.z,q0.w,q1.x,q1.y,q1.z,q1.w};
        float kv[8] = {k0.x,k0.y,k0.z,k0.w,k1.x,k1.y,k1.z,k1.w};
#pragma unroll
        for (int e = 0; e < 8; e++) {
            int c = head * 64 + d0 + e;
            wqk[toff(c, h, 1024)]        = (_Float16)qv[e];
            wqk[toff(c + 1024, h, 1024)] = (_Float16)kv[e];
        }
    } else if (blk < 2816) {                       // cast Wv/Wo
        int i = (blk - 2560) * 256 + tid;
        int d = i >> 10, h = i & 1023;
        wvt[toff(d, h, 1024)] = (_Float16)Wv[(size_t)h * 64 + d];
        int hh = i >> 6, dd = i & 63;
        wot[toff(hh, dd, 64)] = (_Float16)Wo[(size_t)dd * 1024 + hh];
    } else {                                       // zero upper-tri tiles (992)
        int iz = blk - 2816;
        int b = (iz >= 496) ? 1 : 0;
        int i = iz - b * 496;
        int s64 = (int)((sqrtf(8.f * i + 1.f) + 1.f) * 0.5f);
        if (s64 * (s64 - 1) / 2 > i) s64--;
        if ((s64 + 1) * s64 / 2 <= i) s64++;
        int q64 = i - s64 * (s64 - 1) / 2;         // q64 < s64
        float4 z = {0.f, 0.f, 0.f, 0.f};
#pragma unroll
        for (int it = 0; it < 4; it++) {
            int idx = it * 256 + tid;
            int r = idx >> 4, c4 = idx & 15;
            *(float4*)&mw[(size_t)(b * T_ + q64 * 64 + r) * T_ + s64 * 64 + c4 * 4] = z;
        }
    }
}

// ---------- fused: Q||K GEMM (blocks 0..511, BK=64) + V projection (blocks 512..767) ----------
__global__ __launch_bounds__(256) void k_gemm(const _Float16* __restrict__ xb, const _Float16* __restrict__ wqk,
                                              const float* __restrict__ bq, const float* __restrict__ bk,
                                              const _Float16* __restrict__ wvt, const float* __restrict__ bv,
                                              _Float16* __restrict__ qh, _Float16* __restrict__ kh,
                                              _Float16* __restrict__ vt) {
    __shared__ __align__(16) unsigned char smem[32768];
    _Float16* As = (_Float16*)smem;                // 16 KB
    _Float16* Bs = (_Float16*)(smem + 16384);      // 16 KB
    int tid = threadIdx.x, w = tid >> 6, lane = tid & 63, l15 = lane & 15, quad = lane >> 4;
    if (blockIdx.x >= 512) {                       // ---- vproj path ----
        float (*red)[16][64] = (float(*)[16][64])smem;
        int rt = blockIdx.x - 512;
        f32x4 acc[4];
#pragma unroll
        for (int j = 0; j < 4; j++) acc[j] = (f32x4){0.f, 0.f, 0.f, 0.f};
        for (int q = 0; q < 8; q++) {
            int kc = w * 8 + q;
            f16x8 a = frag_ld(xb, rt, kc, 32, l15, quad);
#pragma unroll
            for (int j = 0; j < 4; j++) {
                f16x8 bb = frag_ld(wvt, j, kc, 32, l15, quad);
                acc[j] = MFMA(a, bb, acc[j]);
            }
        }
#pragma unroll
        for (int j = 0; j < 4; j++)
#pragma unroll
            for (int r = 0; r < 4; r++) red[w][quad * 4 + r][j * 16 + l15] = acc[j][r];
        __syncthreads();
        int r = tid >> 4, dg = tid & 15;
        int b = rt >> 7, tt = (rt & 127) * 16 + r;
        _Float16* vtb = vt + (size_t)b * 131072;
#pragma unroll
        for (int e = 0; e < 4; e++) {
            int d = dg * 4 + e;
            float s = red[0][r][d] + red[1][r][d] + red[2][r][d] + red[3][r][d] + bv[d];
            vtb[toff(d, tt, 2048)] = (_Float16)s;
        }
        return;
    }
    // ---- GEMM path, BK=64 ----
    int bm = blockIdx.x >> 4, bn = blockIdx.x & 15;
    int rowbase = (w >> 1) * 64, colbase = (w & 1) * 64;
    f32x4 acc[4][4];
#pragma unroll
    for (int i = 0; i < 4; i++)
#pragma unroll
        for (int j = 0; j < 4; j++) acc[i][j] = (f32x4){0.f, 0.f, 0.f, 0.f};

    for (int kk = 0; kk < 16; kk++) {
        __syncthreads();
#pragma unroll
        for (int p = 0; p < 4; p++) {
            int c = w * 4 + p;                     // 0..15: rowtile c>>1, k-chunk c&1
            __builtin_amdgcn_global_load_lds((GV*)(xb  + ((size_t)((bm * 8 + (c >> 1)) * 32 + kk * 2 + (c & 1))) * 512 + lane * 8),
                                             (LV*)(As + c * 512 + lane * 8), 16, 0, 0);
            __builtin_amdgcn_global_load_lds((GV*)(wqk + ((size_t)((bn * 8 + (c >> 1)) * 32 + kk * 2 + (c & 1))) * 512 + lane * 8),
                                             (LV*)(Bs + c * 512 + lane * 8), 16, 0, 0);
        }
        __syncthreads();
#pragma unroll
        for (int kc = 0; kc < 2; kc++) {
            f16x8 a[4], bf[4];
#pragma unroll
            for (int i = 0; i < 4; i++) a[i]  = *(const f16x8*)&As[((rowbase >> 4) + i) * 1024 + kc * 512 + quad * 128 + l15 * 8];
#pragma unroll
            for (int j = 0; j < 4; j++) bf[j] = *(const f16x8*)&Bs[((colbase >> 4) + j) * 1024 + kc * 512 + quad * 128 + l15 * 8];
#pragma unroll
            for (int i = 0; i < 4; i++)
#pragma unroll
                for (int j = 0; j < 4; j++) acc[i][j] = MFMA(a[i], bf[j], acc[i][j]);
        }
    }
    __syncthreads();                               // reuse As/Bs for epilogue staging
    int b = (bm * 128) >> 11;
    int t_base = (bm * 128) & 2047;
    int rtbase = (t_base + rowbase) >> 4;
    bool isq = (bn < 8);
    int c2base = isq ? (bn * 128 + colbase) : (bn * 128 + colbase - 1024);
    int n = c2base >> 6;
    _Float16* dst = (isq ? qh : kh) + (size_t)(n * 2 + b) * 131072;
    const float* bias_p = isq ? bq : bk;
    float qs = SCALE_ * LOG2E_;                    // fold softmax scale + log2e into q
    int i2 = lane >> 4, rowrb = lane & 15;
#pragma unroll
    for (int j = 0; j < 4; j++) {
        float bias = bias_p[c2base + j * 16 + l15];
        _Float16* stg = ((j & 1) ? Bs : As) + w * 1024;
#pragma unroll
        for (int i = 0; i < 4; i++)
#pragma unroll
            for (int r = 0; r < 4; r++) {
                float v = acc[i][j][r] + bias;
                if (isq) v *= qs;
                stg[(i * 16 + quad * 4 + r) * 16 + l15] = (_Float16)v;
            }
#pragma unroll
        for (int oct = 0; oct < 2; oct++) {
            f16x8 val = *(const f16x8*)&stg[(i2 * 16 + rowrb) * 16 + oct * 8];
            int dd0 = j * 16 + oct * 8;
            *(f16x8*)(dst + (size_t)((rtbase + i2) * 2 + (dd0 >> 5)) * 512 + ((dd0 & 31) >> 3) * 128 + rowrb * 8) = val;
        }
    }
}

// ---------- pass 1: causal row sum-exp2; 32-row strips, 4-way K-split -> 8 waves/SIMD ----------
__global__ __launch_bounds__(256) void k_pass1(const _Float16* __restrict__ qh, const _Float16* __restrict__ kh,
                                               float* __restrict__ lstat4) {
    int tid = threadIdx.x, w = tid >> 6, lane = tid & 63, l15 = lane & 15, quad = lane >> 4;
    int blk = blockIdx.x;                          // 2048 blocks
    int n = blk >> 7, b = (blk >> 6) & 1, s2 = blk & 63;
    const _Float16* qb = qh + (size_t)(n * 2 + b) * 131072;
    const _Float16* kp = kh + (size_t)(n * 2 + b) * 131072;
    int rt0 = s2 * 2;
    f16x8 aq[2][2];
#pragma unroll
    for (int i = 0; i < 2; i++)
#pragma unroll
        for (int kk = 0; kk < 2; kk++) aq[i][kk] = frag_ld(qb, rt0 + i, kk, 2, l15, quad);
    float l[2][4];
#pragma unroll
    for (int i = 0; i < 2; i++)
#pragma unroll
        for (int r = 0; r < 4; r++) l[i][r] = 0.f;
    int total = 2 * s2 + 2;
    int st_lo = (w * total) >> 2;
    int st_hi = ((w + 1) * total) >> 2;
    for (int st = st_lo; st < st_hi; st++) {
        f16x8 c0 = frag_ld(kp, st, 0, 2, l15, quad);
        f16x8 c1 = frag_ld(kp, st, 1, 2, l15, quad);
#pragma unroll
        for (int i = 0; i < 2; i++) {
            if (st > rt0 + i) continue;            // wave-uniform branch
            f32x4 sc = (f32x4){0.f, 0.f, 0.f, 0.f};
            sc = MFMA(aq[i][0], c0, sc);
            sc = MFMA(aq[i][1], c1, sc);
            if (st == rt0 + i) {
#pragma unroll
                for (int r = 0; r < 4; r++)
                    if (l15 <= quad * 4 + r) l[i][r] += EXP2(sc[r]);
            } else {
#pragma unroll
                for (int r = 0; r < 4; r++) l[i][r] += EXP2(sc[r]);
            }
        }
    }
#pragma unroll
    for (int off = 1; off < 16; off <<= 1)
#pragma unroll
        for (int i = 0; i < 2; i++)
#pragma unroll
            for (int r = 0; r < 4; r++) l[i][r] += __shfl_xor(l[i][r], off, 64);
    if (l15 == 0) {
        int base = (n * 2 + b) * 2048 + s2 * 32;
#pragma unroll
        for (int i = 0; i < 2; i++)
#pragma unroll
            for (int r = 0; r < 4; r++)
                lstat4[(size_t)(base + i * 16 + quad * 4 + r) * 4 + w] = l[i][r];
    }
}

// ---------- pass 2: 64q x 64s tiles (1056 blocks), dbuf LDS K-stage, exp-fold via MFMA C-init ----------
__global__ __launch_bounds__(256, 4) void k_pass2(const _Float16* __restrict__ qh, const _Float16* __restrict__ kh,
                                                  const float* __restrict__ lstat4,
                                                  float* __restrict__ mw, _Float16* __restrict__ mwh) {
    __shared__ float sl[16][64];                   // 4 KB: per-(head,row) log2 bias m
    __shared__ __align__(16) _Float16 kst[2][4096];// 16 KB double-buffered K stage (+store transpose)
    int blk = blockIdx.x;                          // 1056 = 2b x 528
    int b = (blk >= 528) ? 1 : 0;
    int i0 = blk - 528 * b;
    int i = (i0 & 7) * 66 + (i0 >> 3);             // XCD-banded (528 = 8 x 66)
    int p = (int)((sqrtf(8.f * i + 1.f) - 1.f) * 0.5f);
    while (p * (p + 1) / 2 > i) p--;
    while ((p + 1) * (p + 2) / 2 <= i) p++;
    int s64 = i - p * (p + 1) / 2;                 // s64 in [0, p]
    bool masked = (s64 == p);                      // diagonal tile
    int tid = threadIdx.x, w = tid >> 6, lane = tid & 63, l15 = lane & 15, quad = lane >> 4;
    for (int ii = tid; ii < 1024; ii += 256) {
        int h = ii >> 6, r = ii & 63;
        const float4 pl = *(const float4*)&lstat4[(size_t)((h * 2 + b) * 2048 + p * 64 + r) * 4];
        sl[h][r] = -(__log2f(pl.x + pl.y + pl.z + pl.w) + 4.0f);  // fold 1/sum and 1/16 into exp arg
    }
    int rw = w * 16;
    int rt0 = p * 4 + w;                           // q row-tile (1 per wave)
    int st0 = s64 * 4;                             // k row-tile base (4 per block)
    f32x4 macc[4];
#pragma unroll
    for (int j = 0; j < 4; j++) macc[j] = (f32x4){0.f, 0.f, 0.f, 0.f};

    // prologue: stage K(head 0)
    {
        const _Float16* kp = kh + (size_t)b * 131072;
#pragma unroll
        for (int inst = 0; inst < 2; inst++) {
            int c = inst * 4 + w;
            int gc = (st0 + (c >> 1)) * 2 + (c & 1);
            __builtin_amdgcn_global_load_lds((GV*)(kp + (size_t)gc * 512 + lane * 8),
                                             (LV*)(kst[0] + c * 512 + lane * 8), 16, 0, 0);
        }
    }
    __syncthreads();                               // sl + stage0 ready

    for (int n = 0; n < NH_; n++) {
        if (n < NH_ - 1) {                         // prefetch head n+1's K during compute
            const _Float16* kp = kh + (size_t)((n + 1) * 2 + b) * 131072;
#pragma unroll
            for (int inst = 0; inst < 2; inst++) {
                int c = inst * 4 + w;
                int gc = (st0 + (c >> 1)) * 2 + (c & 1);
                __builtin_amdgcn_global_load_lds((GV*)(kp + (size_t)gc * 512 + lane * 8),
                                                 (LV*)(kst[(n + 1) & 1] + c * 512 + lane * 8), 16, 0, 0);
            }
        }
        const _Float16* qb = qh + (size_t)(n * 2 + b) * 131072;
        f16x8 A0 = frag_ld(qb, rt0, 0, 2, l15, quad);
        f16x8 A1 = frag_ld(qb, rt0, 1, 2, l15, quad);
        f32x4 slv = *(const f32x4*)&sl[n][rw + quad * 4];   // per-row log2 bias
        const _Float16* ks = kst[n & 1];
#pragma unroll
        for (int j = 0; j < 4; j++) {
            f16x8 K0 = *(const f16x8*)&ks[(j * 2 + 0) * 512 + quad * 128 + l15 * 8];
            f16x8 K1 = *(const f16x8*)&ks[(j * 2 + 1) * 512 + quad * 128 + l15 * 8];
            f32x4 sc = slv;                        // C-init with bias: MFMA out = score + m
            sc = MFMA(A0, K0, sc);
            sc = MFMA(A1, K1, sc);
            if (masked) {
                int sg = s64 * 64 + j * 16 + l15;
#pragma unroll
                for (int r = 0; r < 4; r++) {
                    int tg = p * 64 + rw + quad * 4 + r;
                    macc[j][r] += (sg <= tg) ? EXP2(sc[r]) : 0.f;
                }
            } else {
#pragma unroll
                for (int r = 0; r < 4; r++) macc[j][r] += EXP2(sc[r]);
            }
        }
        __syncthreads();                           // next stage ready; current reads done
    }
    // fp32 mw store
    float* mwb = mw + (size_t)b * T_ * T_;
#pragma unroll
    for (int j = 0; j < 4; j++)
#pragma unroll
        for (int r = 0; r < 4; r++) {
            int tg = p * 64 + rw + quad * 4 + r;
            int sg = s64 * 64 + j * 16 + l15;
            mwb[(size_t)tg * T_ + sg] = macc[j][r];
        }
    // f16 tiled store via per-wave LDS transpose (2 rounds of 32 cols)
    _Float16* mhb = mwh + (size_t)b * 4194304;
    _Float16* ws16 = kst[0] + w * 1024;            // wave-private 1 KB (post-barrier safe)
    int rowrb = lane & 15, qc = lane >> 4;
#pragma unroll
    for (int cc = 0; cc < 2; cc++) {
#pragma unroll
        for (int j2 = 0; j2 < 2; j2++)
#pragma unroll
            for (int r = 0; r < 4; r++) {
                int clw = j2 * 16 + l15;
                ws16[(clw >> 3) * 128 + (quad * 4 + r) * 8 + (clw & 7)] = (_Float16)macc[cc * 2 + j2][r];
            }
        f16x8 val = *(const f16x8*)&ws16[qc * 128 + rowrb * 8];
        *(f16x8*)(mhb + (size_t)(rt0 * 64 + (s64 * 2 + cc)) * 512 + qc * 128 + rowrb * 8) = val;
    }
}

// ---------- pass 3a: mean_head partials; block = (tile16, k-quarter) ----------
__global__ __launch_bounds__(256) void k_pass3a(const _Float16* __restrict__ mwh, const _Float16* __restrict__ vt,
                                                _Float16* __restrict__ mhp) {
    __shared__ float red[4][16][64];
    int tid = threadIdx.x, w = tid >> 6, lane = tid & 63, l15 = lane & 15, quad = lane >> 4;
    int blk = blockIdx.x;                          // 1024 = 256 tiles x 4 quarters
    int tile = blk >> 2, q = blk & 3;
    int b = tile >> 7, rtb = tile & 127;
    const _Float16* mb = mwh + (size_t)b * 4194304;
    const _Float16* vb = vt + (size_t)b * 131072;
    int nkc = (rtb * 16 + 47) >> 5;
    int qlo = q * 16;
    int qhi = min(qlo + 16, nkc);
    f32x4 acc[4];
#pragma unroll
    for (int j = 0; j < 4; j++) acc[j] = (f32x4){0.f, 0.f, 0.f, 0.f};
    for (int kc = qlo + w; kc < qhi; kc += 4) {
        f16x8 a = frag_ld(mb, rtb, kc, 64, l15, quad);
#pragma unroll
        for (int j = 0; j < 4; j++) {
            f16x8 bb = frag_ld(vb, j, kc, 64, l15, quad);
            acc[j] = MFMA(a, bb, acc[j]);
        }
    }
#pragma unroll
    for (int j = 0; j < 4; j++)
#pragma unroll
        for (int r = 0; r < 4; r++) red[w][quad * 4 + r][j * 16 + l15] = acc[j][r];
    __syncthreads();
    int r = tid >> 4, dg = tid & 15;
    _Float16* dst = mhp + (size_t)q * 262144;
#pragma unroll
    for (int e = 0; e < 4; e++) {
        int d = dg * 4 + e;
        float s = red[0][r][d] + red[1][r][d] + red[2][r][d] + red[3][r][d];
        dst[toff(tile * 16 + r, d, 64)] = (_Float16)s;
    }
}

// ---------- pass 3b: out = (sum of 4 partials) @ Wo + bo ----------
__global__ __launch_bounds__(256) void k_pass3b(const _Float16* __restrict__ mhp, const _Float16* __restrict__ wot,
                                                const float* __restrict__ bo, float* __restrict__ out0) {
    int bm = blockIdx.x >> 4, bn = blockIdx.x & 15;
    int tid = threadIdx.x, w = tid >> 6, lane = tid & 63, l15 = lane & 15, quad = lane >> 4;
    int rt = bm * 4 + w;
    f16x8 a0[4], a1[4];
#pragma unroll
    for (int q = 0; q < 4; q++) {
        const _Float16* mb = mhp + (size_t)q * 262144;
        a0[q] = frag_ld(mb, rt, 0, 2, l15, quad);
        a1[q] = frag_ld(mb, rt, 1, 2, l15, quad);
    }
    f32x4 acc[4];
#pragma unroll
    for (int j = 0; j < 4; j++) acc[j] = (f32x4){0.f, 0.f, 0.f, 0.f};
#pragma unroll
    for (int j = 0; j < 4; j++) {
        f16x8 b0 = frag_ld(wot, bn * 4 + j, 0, 2, l15, quad);
        f16x8 b1 = frag_ld(wot, bn * 4 + j, 1, 2, l15, quad);
#pragma unroll
        for (int q = 0; q < 4; q++) {
            acc[j] = MFMA(a0[q], b0, acc[j]);
            acc[j] = MFMA(a1[q], b1, acc[j]);
        }
    }
#pragma unroll
    for (int j = 0; j < 4; j++)
#pragma unroll
        for (int r = 0; r < 4; r++) {
            int row = rt * 16 + quad * 4 + r;
            int col = bn * 64 + j * 16 + l15;
            out0[(size_t)row * 1024 + col] = acc[j][r] + bo[col];
        }
}

extern "C" void kernel_launch(void* const* d_in, const int* in_sizes, int n_in,
                              void* d_out, int out_size, void* d_ws, size_t ws_size,
                              hipStream_t stream) {
    const float* x  = (const float*)d_in[0];
    const float* Wq = (const float*)d_in[1];
    const float* bq = (const float*)d_in[2];
    const float* Wk = (const float*)d_in[3];
    const float* bk = (const float*)d_in[4];
    const float* Wv = (const float*)d_in[5];
    const float* bv = (const float*)d_in[6];
    const float* Wo = (const float*)d_in[7];
    const float* bo = (const float*)d_in[8];
    char* ws = (char*)d_ws;
    _Float16* xb    = (_Float16*)(ws + 0);         // 8 MB (dead after gemm/vproj)
    _Float16* wqk   = (_Float16*)(ws + 8388608);   // 4 MB (dead after gemm)
    _Float16* wvt   = (_Float16*)(ws + 12582912);  // 128 KB (dead after vproj)
    _Float16* mwh   = (_Float16*)(ws + 0);         // 16 MB overlay
    _Float16* qh    = (_Float16*)(ws + 16777216);  // 8 MB
    _Float16* kh    = (_Float16*)(ws + 25165824);  // 8 MB
    _Float16* vt    = (_Float16*)(ws + 33554432);  // 512 KB
    float*    lstat4= (float*)   (ws + 34078720);  // 1 MB
    _Float16* mhp   = (_Float16*)(ws + 35127296);  // 2 MB (4 partials)
    _Float16* wot   = (_Float16*)(ws + 37224448);  // 128 KB
    float* out0 = (float*)d_out;
    float* mw   = out0 + (size_t)BT_ * H_;

    k_prep   <<<3808, 256, 0, stream>>>(x, Wq, Wk, Wv, Wo, xb, wqk, wvt, wot, mw);
    k_gemm   <<<768,  256, 0, stream>>>(xb, wqk, bq, bk, wvt, bv, qh, kh, vt);
    k_pass1  <<<2048, 256, 0, stream>>>(qh, kh, lstat4);
    k_pass2  <<<1056, 256, 0, stream>>>(qh, kh, lstat4, mw, mwh);
    k_pass3a <<<1024, 256, 0, stream>>>(mwh, vt, mhp);
    k_pass3b <<<1024, 256, 0, stream>>>(mhp, wot, bo, out0);
}

// Round 9
// 191.150 us; speedup vs baseline: 1.2789x; 1.0299x over previous
//
#include <hip/hip_runtime.h>
#include <hip/hip_bf16.h>

#define B_ 2
#define T_ 2048
#define H_ 1024
#define NH_ 16
#define D_ 64
#define BT_ (B_*T_)
#define SCALE_ 0.125f
#define LOG2E_ 1.4426950408889634f

typedef _Float16 f16x8 __attribute__((ext_vector_type(8)));
typedef float f32x4 __attribute__((ext_vector_type(4)));

#define MFMA(a,b,c) __builtin_amdgcn_mfma_f32_16x16x32_f16((a),(b),(c),0,0,0)
#define EXP2(x) __builtin_amdgcn_exp2f(x)

typedef const __attribute__((address_space(1))) void GV;
typedef __attribute__((address_space(3))) void LV;

// Fragment-tiled layout: matrix [R x C] consumed by MFMA with k-dim = C.
// 16-row tiles, 32-wide k-chunks; chunk block = [quad(k/8)][row%16][k%8] = 512 f16 = 1KB.
__device__ __forceinline__ size_t toff(int r, int c, int C) {
    return (size_t)((r >> 4) * (C >> 5) + (c >> 5)) * 512 + (size_t)(((c & 31) >> 3) * 128 + (r & 15) * 8 + (c & 7));
}
__device__ __forceinline__ f16x8 frag_ld(const _Float16* base, int rt, int kc, int Cc, int l15, int quad) {
    return *(const f16x8*)(base + (size_t)(rt * Cc + kc) * 512 + quad * 128 + l15 * 8);
}

// ---------- prep: cast x, cast Wq/Wk, cast Wv/Wo, zero upper-tri mw — one kernel ----------
__global__ __launch_bounds__(256) void k_prep(const float* __restrict__ x,
                                              const float* __restrict__ Wq, const float* __restrict__ Wk,
                                              const float* __restrict__ Wv, const float* __restrict__ Wo,
                                              _Float16* __restrict__ xb, _Float16* __restrict__ wqk,
                                              _Float16* __restrict__ wvt, _Float16* __restrict__ wot,
                                              float* __restrict__ mw) {
    int blk = blockIdx.x, tid = threadIdx.x;
    if (blk < 2048) {                              // cast x
        int idx = blk * 256 + tid;
        int t = idx >> 7, h0 = (idx & 127) * 8;
        const float* p = x + ((size_t)t << 10) + h0;
        float4 f0 = *(const float4*)p;
        float4 f1 = *(const float4*)(p + 4);
        f16x8 o;
        o[0]=(_Float16)f0.x; o[1]=(_Float16)f0.y; o[2]=(_Float16)f0.z; o[3]=(_Float16)f0.w;
        o[4]=(_Float16)f1.x; o[5]=(_Float16)f1.y; o[6]=(_Float16)f1.z; o[7]=(_Float16)f1.w;
        *(f16x8*)(xb + toff(t, h0, 1024)) = o;
    } else if (blk < 2560) {                       // cast Wq/Wk
        int idx = (blk - 2048) * 256 + tid;
        int head = idx >> 13;
        int rem = idx & 8191;
        int h = rem >> 3;
        int d0 = (rem & 7) * 8;
        const float* pq = Wq + ((size_t)((head << 10) + h)) * 64 + d0;
        const float* pk = Wk + ((size_t)((head << 10) + h)) * 64 + d0;
        float4 q0 = *(const float4*)pq, q1 = *(const float4*)(pq + 4);
        float4 k0 = *(const float4*)pk, k1 = *(const float4*)(pk + 4);
        float qv[8] = {q0.x,q0.y,q0.z,q0.w,q1.x,q1.y,q1.z,q1.w};
        float kv[8] = {k0.x,k0.y,k0.z,k0.w,k1.x,k1.y,k1.z,k1.w};
#pragma unroll
        for (int e = 0; e < 8; e++) {
            int c = head * 64 + d0 + e;
            wqk[toff(c, h, 1024)]        = (_Float16)qv[e];
            wqk[toff(c + 1024, h, 1024)] = (_Float16)kv[e];
        }
    } else if (blk < 2816) {                       // cast Wv/Wo
        int i = (blk - 2560) * 256 + tid;
        int d = i >> 10, h = i & 1023;
        wvt[toff(d, h, 1024)] = (_Float16)Wv[(size_t)h * 64 + d];
        int hh = i >> 6, dd = i & 63;
        wot[toff(hh, dd, 64)] = (_Float16)Wo[(size_t)dd * 1024 + hh];
    } else {                                       // zero upper-tri tiles (992)
        int iz = blk - 2816;
        int b = (iz >= 496) ? 1 : 0;
        int i = iz - b * 496;
        int s64 = (int)((sqrtf(8.f * i + 1.f) + 1.f) * 0.5f);
        if (s64 * (s64 - 1) / 2 > i) s64--;
        if ((s64 + 1) * s64 / 2 <= i) s64++;
        int q64 = i - s64 * (s64 - 1) / 2;         // q64 < s64
        float4 z = {0.f, 0.f, 0.f, 0.f};
#pragma unroll
        for (int it = 0; it < 4; it++) {
            int idx = it * 256 + tid;
            int r = idx >> 4, c4 = idx & 15;
            *(float4*)&mw[(size_t)(b * T_ + q64 * 64 + r) * T_ + s64 * 64 + c4 * 4] = z;
        }
    }
}

// ---------- fused: Q||K GEMM (blocks 0..511, BK=64) + V projection (blocks 512..767) ----------
__global__ __launch_bounds__(256) void k_gemm(const _Float16* __restrict__ xb, const _Float16* __restrict__ wqk,
                                              const float* __restrict__ bq, const float* __restrict__ bk,
                                              const _Float16* __restrict__ wvt, const float* __restrict__ bv,
                                              _Float16* __restrict__ qh, _Float16* __restrict__ kh,
                                              _Float16* __restrict__ vt) {
    __shared__ __align__(16) unsigned char smem[32768];
    _Float16* As = (_Float16*)smem;                // 16 KB
    _Float16* Bs = (_Float16*)(smem + 16384);      // 16 KB
    int tid = threadIdx.x, w = tid >> 6, lane = tid & 63, l15 = lane & 15, quad = lane >> 4;
    if (blockIdx.x >= 512) {                       // ---- vproj path ----
        float (*red)[16][64] = (float(*)[16][64])smem;
        int rt = blockIdx.x - 512;
        f32x4 acc[4];
#pragma unroll
        for (int j = 0; j < 4; j++) acc[j] = (f32x4){0.f, 0.f, 0.f, 0.f};
        for (int q = 0; q < 8; q++) {
            int kc = w * 8 + q;
            f16x8 a = frag_ld(xb, rt, kc, 32, l15, quad);
#pragma unroll
            for (int j = 0; j < 4; j++) {
                f16x8 bb = frag_ld(wvt, j, kc, 32, l15, quad);
                acc[j] = MFMA(a, bb, acc[j]);
            }
        }
#pragma unroll
        for (int j = 0; j < 4; j++)
#pragma unroll
            for (int r = 0; r < 4; r++) red[w][quad * 4 + r][j * 16 + l15] = acc[j][r];
        __syncthreads();
        int r = tid >> 4, dg = tid & 15;
        int b = rt >> 7, tt = (rt & 127) * 16 + r;
        _Float16* vtb = vt + (size_t)b * 131072;
#pragma unroll
        for (int e = 0; e < 4; e++) {
            int d = dg * 4 + e;
            float s = red[0][r][d] + red[1][r][d] + red[2][r][d] + red[3][r][d] + bv[d];
            vtb[toff(d, tt, 2048)] = (_Float16)s;
        }
        return;
    }
    // ---- GEMM path, BK=64 ----
    int bm = blockIdx.x >> 4, bn = blockIdx.x & 15;
    int rowbase = (w >> 1) * 64, colbase = (w & 1) * 64;
    f32x4 acc[4][4];
#pragma unroll
    for (int i = 0; i < 4; i++)
#pragma unroll
        for (int j = 0; j < 4; j++) acc[i][j] = (f32x4){0.f, 0.f, 0.f, 0.f};

    for (int kk = 0; kk < 16; kk++) {
        __syncthreads();
#pragma unroll
        for (int p = 0; p < 4; p++) {
            int c = w * 4 + p;                     // 0..15: rowtile c>>1, k-chunk c&1
            __builtin_amdgcn_global_load_lds((GV*)(xb  + ((size_t)((bm * 8 + (c >> 1)) * 32 + kk * 2 + (c & 1))) * 512 + lane * 8),
                                             (LV*)(As + c * 512 + lane * 8), 16, 0, 0);
            __builtin_amdgcn_global_load_lds((GV*)(wqk + ((size_t)((bn * 8 + (c >> 1)) * 32 + kk * 2 + (c & 1))) * 512 + lane * 8),
                                             (LV*)(Bs + c * 512 + lane * 8), 16, 0, 0);
        }
        __syncthreads();
#pragma unroll
        for (int kc = 0; kc < 2; kc++) {
            f16x8 a[4], bf[4];
#pragma unroll
            for (int i = 0; i < 4; i++) a[i]  = *(const f16x8*)&As[((rowbase >> 4) + i) * 1024 + kc * 512 + quad * 128 + l15 * 8];
#pragma unroll
            for (int j = 0; j < 4; j++) bf[j] = *(const f16x8*)&Bs[((colbase >> 4) + j) * 1024 + kc * 512 + quad * 128 + l15 * 8];
#pragma unroll
            for (int i = 0; i < 4; i++)
#pragma unroll
                for (int j = 0; j < 4; j++) acc[i][j] = MFMA(a[i], bf[j], acc[i][j]);
        }
    }
    __syncthreads();                               // reuse As/Bs for epilogue staging
    int b = (bm * 128) >> 11;
    int t_base = (bm * 128) & 2047;
    int rtbase = (t_base + rowbase) >> 4;
    bool isq = (bn < 8);
    int c2base = isq ? (bn * 128 + colbase) : (bn * 128 + colbase - 1024);
    int n = c2base >> 6;
    _Float16* dst = (isq ? qh : kh) + (size_t)(n * 2 + b) * 131072;
    const float* bias_p = isq ? bq : bk;
    float qs = SCALE_ * LOG2E_;                    // fold softmax scale + log2e into q
    int i2 = lane >> 4, rowrb = lane & 15;
#pragma unroll
    for (int j = 0; j < 4; j++) {
        float bias = bias_p[c2base + j * 16 + l15];
        _Float16* stg = ((j & 1) ? Bs : As) + w * 1024;
#pragma unroll
        for (int i = 0; i < 4; i++)
#pragma unroll
            for (int r = 0; r < 4; r++) {
                float v = acc[i][j][r] + bias;
                if (isq) v *= qs;
                stg[(i * 16 + quad * 4 + r) * 16 + l15] = (_Float16)v;
            }
#pragma unroll
        for (int oct = 0; oct < 2; oct++) {
            f16x8 val = *(const f16x8*)&stg[(i2 * 16 + rowrb) * 16 + oct * 8];
            int dd0 = j * 16 + oct * 8;
            *(f16x8*)(dst + (size_t)((rtbase + i2) * 2 + (dd0 >> 5)) * 512 + ((dd0 & 31) >> 3) * 128 + rowrb * 8) = val;
        }
    }
}

// ---------- pass 1: causal row sum-exp2; 32-row strips, XCD-local (n,b) in low block bits ----------
__global__ __launch_bounds__(256) void k_pass1(const _Float16* __restrict__ qh, const _Float16* __restrict__ kh,
                                               float* __restrict__ lstat4) {
    int tid = threadIdx.x, w = tid >> 6, lane = tid & 63, l15 = lane & 15, quad = lane >> 4;
    int blk = blockIdx.x;                          // 2048 blocks: s2(6) | nb(5)
    int nb = blk & 31;                             // blk&7 ~ XCD -> each XCD serves 4 (n,b) pairs
    int s2 = blk >> 5;
    int n = nb >> 1, b = nb & 1;
    const _Float16* qb = qh + (size_t)(n * 2 + b) * 131072;
    const _Float16* kp = kh + (size_t)(n * 2 + b) * 131072;
    int rt0 = s2 * 2;
    f16x8 aq[2][2];
#pragma unroll
    for (int i = 0; i < 2; i++)
#pragma unroll
        for (int kk = 0; kk < 2; kk++) aq[i][kk] = frag_ld(qb, rt0 + i, kk, 2, l15, quad);
    float l[2][4];
#pragma unroll
    for (int i = 0; i < 2; i++)
#pragma unroll
        for (int r = 0; r < 4; r++) l[i][r] = 0.f;
    int total = 2 * s2 + 2;
    int st_lo = (w * total) >> 2;
    int st_hi = ((w + 1) * total) >> 2;
    for (int st = st_lo; st < st_hi; st++) {
        f16x8 c0 = frag_ld(kp, st, 0, 2, l15, quad);
        f16x8 c1 = frag_ld(kp, st, 1, 2, l15, quad);
#pragma unroll
        for (int i = 0; i < 2; i++) {
            if (st > rt0 + i) continue;            // wave-uniform branch
            f32x4 sc = (f32x4){0.f, 0.f, 0.f, 0.f};
            sc = MFMA(aq[i][0], c0, sc);
            sc = MFMA(aq[i][1], c1, sc);
            if (st == rt0 + i) {
#pragma unroll
                for (int r = 0; r < 4; r++)
                    if (l15 <= quad * 4 + r) l[i][r] += EXP2(sc[r]);
            } else {
#pragma unroll
                for (int r = 0; r < 4; r++) l[i][r] += EXP2(sc[r]);
            }
        }
    }
#pragma unroll
    for (int off = 1; off < 16; off <<= 1)
#pragma unroll
        for (int i = 0; i < 2; i++)
#pragma unroll
            for (int r = 0; r < 4; r++) l[i][r] += __shfl_xor(l[i][r], off, 64);
    if (l15 == 0) {
        int base = (n * 2 + b) * 2048 + s2 * 32;
#pragma unroll
        for (int i = 0; i < 2; i++)
#pragma unroll
            for (int r = 0; r < 4; r++)
                lstat4[(size_t)(base + i * 16 + quad * 4 + r) * 4 + w] = l[i][r];
    }
}

// ---------- pass 2: 64q x 64s tiles (1056 blocks), dbuf LDS K-stage, exp-fold via MFMA C-init ----------
__global__ __launch_bounds__(256, 6) void k_pass2(const _Float16* __restrict__ qh, const _Float16* __restrict__ kh,
                                                  const float* __restrict__ lstat4,
                                                  float* __restrict__ mw, _Float16* __restrict__ mwh) {
    __shared__ float sl[16][64];                   // 4 KB: per-(head,row) log2 bias m
    __shared__ __align__(16) _Float16 kst[2][4096];// 16 KB double-buffered K stage (+store transpose)
    int blk = blockIdx.x;                          // 1056 = 2b x 528
    int b = (blk >= 528) ? 1 : 0;
    int i0 = blk - 528 * b;
    int i = (i0 & 7) * 66 + (i0 >> 3);             // XCD-banded (528 = 8 x 66)
    int p = (int)((sqrtf(8.f * i + 1.f) - 1.f) * 0.5f);
    while (p * (p + 1) / 2 > i) p--;
    while ((p + 1) * (p + 2) / 2 <= i) p++;
    int s64 = i - p * (p + 1) / 2;                 // s64 in [0, p]
    bool masked = (s64 == p);                      // diagonal tile
    int tid = threadIdx.x, w = tid >> 6, lane = tid & 63, l15 = lane & 15, quad = lane >> 4;
    for (int ii = tid; ii < 1024; ii += 256) {
        int h = ii >> 6, r = ii & 63;
        const float4 pl = *(const float4*)&lstat4[(size_t)((h * 2 + b) * 2048 + p * 64 + r) * 4];
        sl[h][r] = -(__log2f(pl.x + pl.y + pl.z + pl.w) + 4.0f);  // fold 1/sum and 1/16 into exp arg
    }
    int rw = w * 16;
    int rt0 = p * 4 + w;                           // q row-tile (1 per wave)
    int st0 = s64 * 4;                             // k row-tile base (4 per block)
    f32x4 macc[4];
#pragma unroll
    for (int j = 0; j < 4; j++) macc[j] = (f32x4){0.f, 0.f, 0.f, 0.f};

    // prologue: stage K(head 0)
    {
        const _Float16* kp = kh + (size_t)b * 131072;
#pragma unroll
        for (int inst = 0; inst < 2; inst++) {
            int c = inst * 4 + w;
            int gc = (st0 + (c >> 1)) * 2 + (c & 1);
            __builtin_amdgcn_global_load_lds((GV*)(kp + (size_t)gc * 512 + lane * 8),
                                             (LV*)(kst[0] + c * 512 + lane * 8), 16, 0, 0);
        }
    }
    __syncthreads();                               // sl + stage0 ready

    for (int n = 0; n < NH_; n++) {
        if (n < NH_ - 1) {                         // prefetch head n+1's K during compute
            const _Float16* kp = kh + (size_t)((n + 1) * 2 + b) * 131072;
#pragma unroll
            for (int inst = 0; inst < 2; inst++) {
                int c = inst * 4 + w;
                int gc = (st0 + (c >> 1)) * 2 + (c & 1);
                __builtin_amdgcn_global_load_lds((GV*)(kp + (size_t)gc * 512 + lane * 8),
                                                 (LV*)(kst[(n + 1) & 1] + c * 512 + lane * 8), 16, 0, 0);
            }
        }
        const _Float16* qb = qh + (size_t)(n * 2 + b) * 131072;
        f16x8 A0 = frag_ld(qb, rt0, 0, 2, l15, quad);
        f16x8 A1 = frag_ld(qb, rt0, 1, 2, l15, quad);
        f32x4 slv = *(const f32x4*)&sl[n][rw + quad * 4];   // per-row log2 bias
        const _Float16* ks = kst[n & 1];
#pragma unroll
        for (int j = 0; j < 4; j++) {
            f16x8 K0 = *(const f16x8*)&ks[(j * 2 + 0) * 512 + quad * 128 + l15 * 8];
            f16x8 K1 = *(const f16x8*)&ks[(j * 2 + 1) * 512 + quad * 128 + l15 * 8];
            f32x4 sc = slv;                        // C-init with bias: MFMA out = score + m
            sc = MFMA(A0, K0, sc);
            sc = MFMA(A1, K1, sc);
            if (masked) {
                int sg = s64 * 64 + j * 16 + l15;
#pragma unroll
                for (int r = 0; r < 4; r++) {
                    int tg = p * 64 + rw + quad * 4 + r;
                    macc[j][r] += (sg <= tg) ? EXP2(sc[r]) : 0.f;
                }
            } else {
#pragma unroll
                for (int r = 0; r < 4; r++) macc[j][r] += EXP2(sc[r]);
            }
        }
        __syncthreads();                           // next stage ready; current reads done
    }
    // fp32 mw store
    float* mwb = mw + (size_t)b * T_ * T_;
#pragma unroll
    for (int j = 0; j < 4; j++)
#pragma unroll
        for (int r = 0; r < 4; r++) {
            int tg = p * 64 + rw + quad * 4 + r;
            int sg = s64 * 64 + j * 16 + l15;
            mwb[(size_t)tg * T_ + sg] = macc[j][r];
        }
    // f16 tiled store via per-wave LDS transpose (2 rounds of 32 cols)
    _Float16* mhb = mwh + (size_t)b * 4194304;
    _Float16* ws16 = kst[0] + w * 1024;            // wave-private 1 KB (post-barrier safe)
    int rowrb = lane & 15, qc = lane >> 4;
#pragma unroll
    for (int cc = 0; cc < 2; cc++) {
#pragma unroll
        for (int j2 = 0; j2 < 2; j2++)
#pragma unroll
            for (int r = 0; r < 4; r++) {
                int clw = j2 * 16 + l15;
                ws16[(clw >> 3) * 128 + (quad * 4 + r) * 8 + (clw & 7)] = (_Float16)macc[cc * 2 + j2][r];
            }
        f16x8 val = *(const f16x8*)&ws16[qc * 128 + rowrb * 8];
        *(f16x8*)(mhb + (size_t)(rt0 * 64 + (s64 * 2 + cc)) * 512 + qc * 128 + rowrb * 8) = val;
    }
}

// ---------- pass 3a: mean_head partials; block = (tile16, k-eighth) -> 2048 blocks ----------
__global__ __launch_bounds__(256) void k_pass3a(const _Float16* __restrict__ mwh, const _Float16* __restrict__ vt,
                                                _Float16* __restrict__ mhp) {
    __shared__ float red[4][16][64];
    int tid = threadIdx.x, w = tid >> 6, lane = tid & 63, l15 = lane & 15, quad = lane >> 4;
    int blk = blockIdx.x;                          // 2048 = 256 tiles x 8 eighths
    int tile = blk >> 3, q = blk & 7;
    int b = tile >> 7, rtb = tile & 127;
    const _Float16* mb = mwh + (size_t)b * 4194304;
    const _Float16* vb = vt + (size_t)b * 131072;
    int nkc = (rtb * 16 + 47) >> 5;
    int qlo = q * 8;
    int qhi = min(qlo + 8, nkc);
    f32x4 acc[4];
#pragma unroll
    for (int j = 0; j < 4; j++) acc[j] = (f32x4){0.f, 0.f, 0.f, 0.f};
    for (int kc = qlo + w; kc < qhi; kc += 4) {
        f16x8 a = frag_ld(mb, rtb, kc, 64, l15, quad);
#pragma unroll
        for (int j = 0; j < 4; j++) {
            f16x8 bb = frag_ld(vb, j, kc, 64, l15, quad);
            acc[j] = MFMA(a, bb, acc[j]);
        }
    }
#pragma unroll
    for (int j = 0; j < 4; j++)
#pragma unroll
        for (int r = 0; r < 4; r++) red[w][quad * 4 + r][j * 16 + l15] = acc[j][r];
    __syncthreads();
    int r = tid >> 4, dg = tid & 15;
    _Float16* dst = mhp + (size_t)q * 262144;
#pragma unroll
    for (int e = 0; e < 4; e++) {
        int d = dg * 4 + e;
        float s = red[0][r][d] + red[1][r][d] + red[2][r][d] + red[3][r][d];
        dst[toff(tile * 16 + r, d, 64)] = (_Float16)s;
    }
}

// ---------- pass 3b: out = (sum of 8 partials) @ Wo + bo ----------
__global__ __launch_bounds__(256) void k_pass3b(const _Float16* __restrict__ mhp, const _Float16* __restrict__ wot,
                                                const float* __restrict__ bo, float* __restrict__ out0) {
    int bm = blockIdx.x >> 4, bn = blockIdx.x & 15;
    int tid = threadIdx.x, w = tid >> 6, lane = tid & 63, l15 = lane & 15, quad = lane >> 4;
    int rt = bm * 4 + w;
    f16x8 a0[8], a1[8];
#pragma unroll
    for (int q = 0; q < 8; q++) {
        const _Float16* mb = mhp + (size_t)q * 262144;
        a0[q] = frag_ld(mb, rt, 0, 2, l15, quad);
        a1[q] = frag_ld(mb, rt, 1, 2, l15, quad);
    }
    f32x4 acc[4];
#pragma unroll
    for (int j = 0; j < 4; j++) acc[j] = (f32x4){0.f, 0.f, 0.f, 0.f};
#pragma unroll
    for (int j = 0; j < 4; j++) {
        f16x8 b0 = frag_ld(wot, bn * 4 + j, 0, 2, l15, quad);
        f16x8 b1 = frag_ld(wot, bn * 4 + j, 1, 2, l15, quad);
#pragma unroll
        for (int q = 0; q < 8; q++) {
            acc[j] = MFMA(a0[q], b0, acc[j]);
            acc[j] = MFMA(a1[q], b1, acc[j]);
        }
    }
#pragma unroll
    for (int j = 0; j < 4; j++)
#pragma unroll
        for (int r = 0; r < 4; r++) {
            int row = rt * 16 + quad * 4 + r;
            int col = bn * 64 + j * 16 + l15;
            out0[(size_t)row * 1024 + col] = acc[j][r] + bo[col];
        }
}

extern "C" void kernel_launch(void* const* d_in, const int* in_sizes, int n_in,
                              void* d_out, int out_size, void* d_ws, size_t ws_size,
                              hipStream_t stream) {
    const float* x  = (const float*)d_in[0];
    const float* Wq = (const float*)d_in[1];
    const float* bq = (const float*)d_in[2];
    const float* Wk = (const float*)d_in[3];
    const float* bk = (const float*)d_in[4];
    const float* Wv = (const float*)d_in[5];
    const float* bv = (const float*)d_in[6];
    const float* Wo = (const float*)d_in[7];
    const float* bo = (const float*)d_in[8];
    char* ws = (char*)d_ws;
    _Float16* xb    = (_Float16*)(ws + 0);         // 8 MB (dead after gemm/vproj)
    _Float16* wqk   = (_Float16*)(ws + 8388608);   // 4 MB (dead after gemm)
    _Float16* wvt   = (_Float16*)(ws + 12582912);  // 128 KB (dead after vproj)
    _Float16* mwh   = (_Float16*)(ws + 0);         // 16 MB overlay
    _Float16* qh    = (_Float16*)(ws + 16777216);  // 8 MB
    _Float16* kh    = (_Float16*)(ws + 25165824);  // 8 MB
    _Float16* vt    = (_Float16*)(ws + 33554432);  // 512 KB
    float*    lstat4= (float*)   (ws + 34078720);  // 1 MB
    _Float16* mhp   = (_Float16*)(ws + 35127296);  // 4 MB (8 partials)
    _Float16* wot   = (_Float16*)(ws + 39321600);  // 128 KB
    float* out0 = (float*)d_out;
    float* mw   = out0 + (size_t)BT_ * H_;

    k_prep   <<<3808, 256, 0, stream>>>(x, Wq, Wk, Wv, Wo, xb, wqk, wvt, wot, mw);
    k_gemm   <<<768,  256, 0, stream>>>(xb, wqk, bq, bk, wvt, bv, qh, kh, vt);
    k_pass1  <<<2048, 256, 0, stream>>>(qh, kh, lstat4);
    k_pass2  <<<1056, 256, 0, stream>>>(qh, kh, lstat4, mw, mwh);
    k_pass3a <<<2048, 256, 0, stream>>>(mwh, vt, mhp);
    k_pass3b <<<1024, 256, 0, stream>>>(mhp, wot, bo, out0);
}